// Round 1
// baseline (951.223 us; speedup 1.0000x reference)
//
#include <hip/hip_runtime.h>

#define N_NODES 50000
#define IN_CH   128
#define HID     128
#define OUT_CH  64

// ---------------- degree / normalization ----------------

__global__ void deg_init_kernel(float* __restrict__ deg) {
    int i = blockIdx.x * 256 + threadIdx.x;
    if (i < N_NODES) deg[i] = 1.0f;  // self-loop
}

__global__ void deg_count_kernel(const int* __restrict__ dst, float* __restrict__ deg, int E) {
    int e = blockIdx.x * 256 + threadIdx.x;
    if (e < E) {
        int d = dst[e];
        if ((unsigned)d < N_NODES) atomicAdd(&deg[d], 1.0f);
    }
}

__global__ void deg_rsqrt_kernel(float* __restrict__ deg) {
    int i = blockIdx.x * 256 + threadIdx.x;
    if (i < N_NODES) deg[i] = rsqrtf(deg[i]);  // deg >= 1 always
}

// ---------------- GEMM1: h1 = x @ W1 ; agg1 = h1 * dinv^2 ----------------
// 256 threads/block, 16 rows/block. W1 is [128][128] row-major.
__global__ __launch_bounds__(256) void gemm1_kernel(
    const float* __restrict__ x, const float* __restrict__ W1,
    const float* __restrict__ dinv,
    float* __restrict__ h1, float* __restrict__ agg1) {
    __shared__ float xs[16][IN_CH];
    const int block_row = blockIdx.x * 16;
    const int tid = threadIdx.x;

    // load 16 rows of x into LDS (2048 floats = 512 float4)
    const float4* xg = (const float4*)(x + (size_t)block_row * IN_CH);
    float4* xs4 = (float4*)(&xs[0][0]);
    #pragma unroll
    for (int i = 0; i < 2; ++i) xs4[tid + 256 * i] = xg[tid + 256 * i];
    __syncthreads();

    const int col = tid & 127;      // 0..127
    const int rg  = tid >> 7;       // 0..1 ; rows rg, rg+2, ..., rg+14
    float acc[8];
    #pragma unroll
    for (int r = 0; r < 8; ++r) acc[r] = 0.0f;

    #pragma unroll 4
    for (int k = 0; k < IN_CH; ++k) {
        float w = W1[k * HID + col];
        #pragma unroll
        for (int r = 0; r < 8; ++r) acc[r] += xs[rg + 2 * r][k] * w;
    }

    #pragma unroll
    for (int r = 0; r < 8; ++r) {
        int row = block_row + rg + 2 * r;   // N_NODES % 16 == 0, always in range
        float v = acc[r];
        float di = dinv[row];
        h1[(size_t)row * HID + col] = v;
        agg1[(size_t)row * HID + col] = v * di * di;   // self-loop contribution
    }
}

// ---------------- scatter layer 1: agg1[d] += h1[s] * dinv[s]*dinv[d] ----------------
// one wave (64 lanes) per edge, lane handles 2 columns (float2)
__global__ __launch_bounds__(256) void scatter1_kernel(
    const int* __restrict__ src, const int* __restrict__ dst,
    const float* __restrict__ dinv, const float* __restrict__ h1,
    float* __restrict__ agg1, int E) {
    int e = blockIdx.x * 4 + (threadIdx.x >> 6);
    int lane = threadIdx.x & 63;
    if (e >= E) return;
    int s = src[e], d = dst[e];
    if ((unsigned)s >= N_NODES || (unsigned)d >= N_NODES) return;
    float w = dinv[s] * dinv[d];
    float2 v = ((const float2*)(h1 + (size_t)s * HID))[lane];
    float* ap = agg1 + (size_t)d * HID + 2 * lane;
    atomicAdd(ap,     v.x * w);
    atomicAdd(ap + 1, v.y * w);
}

// ---------------- GEMM2: a1 = tanh(agg1 + b1); h2 = a1 @ W2 ;
//                  out = b2 + h2 * dinv^2 (self-loop init) ----------------
__global__ __launch_bounds__(256) void gemm2_kernel(
    const float* __restrict__ agg1, const float* __restrict__ b1,
    const float* __restrict__ W2, const float* __restrict__ dinv,
    const float* __restrict__ b2,
    float* __restrict__ h2, float* __restrict__ out) {
    __shared__ float as_[16][HID];
    const int block_row = blockIdx.x * 16;
    const int tid = threadIdx.x;

    // load + activate 16 rows of agg1
    #pragma unroll
    for (int i = 0; i < 8; ++i) {
        int idx = tid + 256 * i;          // 0..2047
        int r = idx >> 7, c = idx & 127;
        as_[r][c] = tanhf(agg1[(size_t)(block_row + r) * HID + c] + b1[c]);
    }
    __syncthreads();

    const int col = tid & 63;   // 0..63
    const int rg  = tid >> 6;   // 0..3 ; rows rg, rg+4, rg+8, rg+12
    float acc[4];
    #pragma unroll
    for (int r = 0; r < 4; ++r) acc[r] = 0.0f;

    #pragma unroll 4
    for (int k = 0; k < HID; ++k) {
        float w = W2[k * OUT_CH + col];
        #pragma unroll
        for (int r = 0; r < 4; ++r) acc[r] += as_[rg + 4 * r][k] * w;
    }

    #pragma unroll
    for (int r = 0; r < 4; ++r) {
        int row = block_row + rg + 4 * r;
        float v = acc[r];
        float di = dinv[row];
        h2[(size_t)row * OUT_CH + col] = v;
        out[(size_t)row * OUT_CH + col] = b2[col] + v * di * di;
    }
}

// ---------------- scatter layer 2: out[d] += h2[s] * dinv[s]*dinv[d] ----------------
// one wave per edge, lane per column (64 cols)
__global__ __launch_bounds__(256) void scatter2_kernel(
    const int* __restrict__ src, const int* __restrict__ dst,
    const float* __restrict__ dinv, const float* __restrict__ h2,
    float* __restrict__ out, int E) {
    int e = blockIdx.x * 4 + (threadIdx.x >> 6);
    int lane = threadIdx.x & 63;
    if (e >= E) return;
    int s = src[e], d = dst[e];
    if ((unsigned)s >= N_NODES || (unsigned)d >= N_NODES) return;
    float w = dinv[s] * dinv[d];
    float v = h2[(size_t)s * OUT_CH + lane];
    atomicAdd(out + (size_t)d * OUT_CH + lane, v * w);
}

extern "C" void kernel_launch(void* const* d_in, const int* in_sizes, int n_in,
                              void* d_out, int out_size, void* d_ws, size_t ws_size,
                              hipStream_t stream) {
    const float* x  = (const float*)d_in[0];
    const int*   ei = (const int*)d_in[1];
    const float* W1 = (const float*)d_in[2];
    const float* b1 = (const float*)d_in[3];
    const float* W2 = (const float*)d_in[4];
    const float* b2 = (const float*)d_in[5];
    float* out = (float*)d_out;

    const int E = in_sizes[1] / 2;   // edge_index is [2, E]
    const int* src = ei;
    const int* dst = ei + E;

    // workspace layout (floats): deg/dinv [N], h1 [N*128], agg1 [N*128], h2 [N*64]
    float* deg  = (float*)d_ws;
    float* h1   = deg  + N_NODES;
    float* agg1 = h1   + (size_t)N_NODES * HID;
    float* h2   = agg1 + (size_t)N_NODES * HID;

    const int nblk_nodes = (N_NODES + 255) / 256;
    const int nblk_edges = (E + 255) / 256;

    deg_init_kernel<<<nblk_nodes, 256, 0, stream>>>(deg);
    deg_count_kernel<<<nblk_edges, 256, 0, stream>>>(dst, deg, E);
    deg_rsqrt_kernel<<<nblk_nodes, 256, 0, stream>>>(deg);

    gemm1_kernel<<<N_NODES / 16, 256, 0, stream>>>(x, W1, deg, h1, agg1);
    scatter1_kernel<<<(E + 3) / 4, 256, 0, stream>>>(src, dst, deg, h1, agg1, E);
    gemm2_kernel<<<N_NODES / 16, 256, 0, stream>>>(agg1, b1, W2, deg, b2, h2, out);
    scatter2_kernel<<<(E + 3) / 4, 256, 0, stream>>>(src, dst, deg, h2, out, E);
}

// Round 2
// 395.002 us; speedup vs baseline: 2.4081x; 2.4081x over previous
//
#include <hip/hip_runtime.h>
#include <stdint.h>

#define N_NODES 50000
#define IN_CH   128
#define HID     128
#define OUT_CH  64

// ---------------- degree / normalization / CSR build ----------------

__global__ void deg_zero_kernel(int* __restrict__ degi) {
    int i = blockIdx.x * 256 + threadIdx.x;
    if (i < N_NODES) degi[i] = 0;
}

__global__ void deg_count_kernel(const int* __restrict__ dst, int* __restrict__ degi, int E) {
    int e = blockIdx.x * 256 + threadIdx.x;
    if (e < E) {
        int d = dst[e];
        if ((unsigned)d < N_NODES) atomicAdd(&degi[d], 1);
    }
}

__global__ void dinv_kernel(const int* __restrict__ degi, float* __restrict__ dinv) {
    int i = blockIdx.x * 256 + threadIdx.x;
    if (i < N_NODES) dinv[i] = rsqrtf(1.0f + (float)degi[i]);  // +1 self-loop
}

// single-block exclusive scan of degi -> offs (also copied to cursor)
#define SCAN_T 1024
#define SCAN_CH ((N_NODES + SCAN_T - 1) / SCAN_T)   // 49
__global__ __launch_bounds__(SCAN_T) void scan_kernel(
    const int* __restrict__ degi, int* __restrict__ offs, int* __restrict__ cursor) {
    __shared__ int part[SCAN_T];
    const int t = threadIdx.x;
    const int base = t * SCAN_CH;
    int s = 0;
    #pragma unroll
    for (int j = 0; j < SCAN_CH; ++j) {
        int idx = base + j;
        if (idx < N_NODES) s += degi[idx];
    }
    part[t] = s;
    __syncthreads();
    // Hillis-Steele inclusive scan over 1024 partials
    for (int off = 1; off < SCAN_T; off <<= 1) {
        int v = (t >= off) ? part[t - off] : 0;
        __syncthreads();
        part[t] += v;
        __syncthreads();
    }
    int run = (t == 0) ? 0 : part[t - 1];
    #pragma unroll
    for (int j = 0; j < SCAN_CH; ++j) {
        int idx = base + j;
        if (idx < N_NODES) {
            offs[idx] = run;
            cursor[idx] = run;
            run += degi[idx];
        }
    }
}

__global__ void bucket_fill_kernel(const int* __restrict__ src, const int* __restrict__ dst,
                                   int* __restrict__ cursor, int* __restrict__ ebuf, int E) {
    int e = blockIdx.x * 256 + threadIdx.x;
    if (e < E) {
        int d = dst[e], s = src[e];
        if ((unsigned)d < N_NODES && (unsigned)s < N_NODES) {
            int pos = atomicAdd(&cursor[d], 1);
            ebuf[pos] = s;
        }
    }
}

// ---------------- GEMM1: h1 = x @ W1 ----------------
__global__ __launch_bounds__(256) void gemm1_kernel(
    const float* __restrict__ x, const float* __restrict__ W1,
    float* __restrict__ h1) {
    __shared__ float xs[16][IN_CH];
    const int block_row = blockIdx.x * 16;
    const int tid = threadIdx.x;

    const float4* xg = (const float4*)(x + (size_t)block_row * IN_CH);
    float4* xs4 = (float4*)(&xs[0][0]);
    #pragma unroll
    for (int i = 0; i < 2; ++i) xs4[tid + 256 * i] = xg[tid + 256 * i];
    __syncthreads();

    const int col = tid & 127;
    const int rg  = tid >> 7;
    float acc[8];
    #pragma unroll
    for (int r = 0; r < 8; ++r) acc[r] = 0.0f;

    #pragma unroll 4
    for (int k = 0; k < IN_CH; ++k) {
        float w = W1[k * HID + col];
        #pragma unroll
        for (int r = 0; r < 8; ++r) acc[r] += xs[rg + 2 * r][k] * w;
    }

    #pragma unroll
    for (int r = 0; r < 8; ++r) {
        int row = block_row + rg + 2 * r;
        h1[(size_t)row * HID + col] = acc[r];
    }
}

// ---------------- gather layer 1: agg1[n] = h1[n]*dinv[n]^2 + sum_e h1[s]*dinv[s]*dinv[n] ----
// one wave per node; lane handles 2 columns
__global__ __launch_bounds__(256) void gather1_kernel(
    const int* __restrict__ offs, const int* __restrict__ degi,
    const int* __restrict__ ebuf, const float* __restrict__ dinv,
    const float* __restrict__ h1, float* __restrict__ agg1) {
    int node = blockIdx.x * 4 + (threadIdx.x >> 6);
    int lane = threadIdx.x & 63;
    if (node >= N_NODES) return;
    float di = dinv[node];
    int beg = offs[node];
    int cnt = degi[node];

    float2 self = ((const float2*)(h1 + (size_t)node * HID))[lane];
    float ax = self.x * di * di;
    float ay = self.y * di * di;

    int i = 0;
    for (; i + 2 <= cnt; i += 2) {
        int s0 = ebuf[beg + i], s1 = ebuf[beg + i + 1];
        float w0 = dinv[s0] * di, w1 = dinv[s1] * di;
        float2 v0 = ((const float2*)(h1 + (size_t)s0 * HID))[lane];
        float2 v1 = ((const float2*)(h1 + (size_t)s1 * HID))[lane];
        ax += v0.x * w0 + v1.x * w1;
        ay += v0.y * w0 + v1.y * w1;
    }
    if (i < cnt) {
        int s0 = ebuf[beg + i];
        float w0 = dinv[s0] * di;
        float2 v0 = ((const float2*)(h1 + (size_t)s0 * HID))[lane];
        ax += v0.x * w0;
        ay += v0.y * w0;
    }
    float2 r; r.x = ax; r.y = ay;
    ((float2*)(agg1 + (size_t)node * HID))[lane] = r;
}

// ---------------- GEMM2: a1 = tanh(agg1 + b1); h2 = a1 @ W2 ----------------
__global__ __launch_bounds__(256) void gemm2_kernel(
    const float* __restrict__ agg1, const float* __restrict__ b1,
    const float* __restrict__ W2, float* __restrict__ h2) {
    __shared__ float as_[16][HID];
    const int block_row = blockIdx.x * 16;
    const int tid = threadIdx.x;

    #pragma unroll
    for (int i = 0; i < 8; ++i) {
        int idx = tid + 256 * i;
        int r = idx >> 7, c = idx & 127;
        as_[r][c] = tanhf(agg1[(size_t)(block_row + r) * HID + c] + b1[c]);
    }
    __syncthreads();

    const int col = tid & 63;
    const int rg  = tid >> 6;
    float acc[4];
    #pragma unroll
    for (int r = 0; r < 4; ++r) acc[r] = 0.0f;

    #pragma unroll 4
    for (int k = 0; k < HID; ++k) {
        float w = W2[k * OUT_CH + col];
        #pragma unroll
        for (int r = 0; r < 4; ++r) acc[r] += as_[rg + 4 * r][k] * w;
    }

    #pragma unroll
    for (int r = 0; r < 4; ++r) {
        int row = block_row + rg + 4 * r;
        h2[(size_t)row * OUT_CH + col] = acc[r];
    }
}

// ---------------- gather layer 2: out[n] = b2 + h2[n]*dinv[n]^2 + sum_e h2[s]*dinv[s]*dinv[n] ----
// one wave per node; lane per column (64)
__global__ __launch_bounds__(256) void gather2_kernel(
    const int* __restrict__ offs, const int* __restrict__ degi,
    const int* __restrict__ ebuf, const float* __restrict__ dinv,
    const float* __restrict__ h2, const float* __restrict__ b2,
    float* __restrict__ out) {
    int node = blockIdx.x * 4 + (threadIdx.x >> 6);
    int lane = threadIdx.x & 63;
    if (node >= N_NODES) return;
    float di = dinv[node];
    int beg = offs[node];
    int cnt = degi[node];

    float acc = b2[lane] + h2[(size_t)node * OUT_CH + lane] * di * di;

    int i = 0;
    for (; i + 2 <= cnt; i += 2) {
        int s0 = ebuf[beg + i], s1 = ebuf[beg + i + 1];
        float w0 = dinv[s0] * di, w1 = dinv[s1] * di;
        float v0 = h2[(size_t)s0 * OUT_CH + lane];
        float v1 = h2[(size_t)s1 * OUT_CH + lane];
        acc += v0 * w0 + v1 * w1;
    }
    if (i < cnt) {
        int s0 = ebuf[beg + i];
        float w0 = dinv[s0] * di;
        acc += h2[(size_t)s0 * OUT_CH + lane] * w0;
    }
    out[(size_t)node * OUT_CH + lane] = acc;
}

extern "C" void kernel_launch(void* const* d_in, const int* in_sizes, int n_in,
                              void* d_out, int out_size, void* d_ws, size_t ws_size,
                              hipStream_t stream) {
    const float* x  = (const float*)d_in[0];
    const int*   ei = (const int*)d_in[1];
    const float* W1 = (const float*)d_in[2];
    const float* b1 = (const float*)d_in[3];
    const float* W2 = (const float*)d_in[4];
    const float* b2 = (const float*)d_in[5];
    float* out = (float*)d_out;

    const int E = in_sizes[1] / 2;   // edge_index is [2, E]
    const int* src = ei;
    const int* dst = ei + E;

    // workspace layout
    float* dinv  = (float*)d_ws;               // N
    int* degi    = (int*)(dinv + N_NODES);     // N
    int* offs    = degi + N_NODES;             // N
    int* cursor  = offs + N_NODES;             // N
    int* ebuf    = cursor + N_NODES;           // E
    uintptr_t p  = (uintptr_t)(ebuf + E);
    p = (p + 15) & ~(uintptr_t)15;
    float* bufA  = (float*)p;                  // N*128 : h1, then h2
    float* bufB  = bufA + (size_t)N_NODES * HID; // N*128 : agg1
    float* h1 = bufA;
    float* agg1 = bufB;
    float* h2 = bufA;

    const int nblk_nodes = (N_NODES + 255) / 256;
    const int nblk_edges = (E + 255) / 256;

    deg_zero_kernel<<<nblk_nodes, 256, 0, stream>>>(degi);
    deg_count_kernel<<<nblk_edges, 256, 0, stream>>>(dst, degi, E);
    dinv_kernel<<<nblk_nodes, 256, 0, stream>>>(degi, dinv);
    scan_kernel<<<1, SCAN_T, 0, stream>>>(degi, offs, cursor);
    bucket_fill_kernel<<<nblk_edges, 256, 0, stream>>>(src, dst, cursor, ebuf, E);

    gemm1_kernel<<<N_NODES / 16, 256, 0, stream>>>(x, W1, h1);
    gather1_kernel<<<(N_NODES + 3) / 4, 256, 0, stream>>>(offs, degi, ebuf, dinv, h1, agg1);
    gemm2_kernel<<<N_NODES / 16, 256, 0, stream>>>(agg1, b1, W2, h2);
    gather2_kernel<<<(N_NODES + 3) / 4, 256, 0, stream>>>(offs, degi, ebuf, dinv, h2, b2, out);
}

// Round 3
// 294.970 us; speedup vs baseline: 3.2248x; 1.3391x over previous
//
#include <hip/hip_runtime.h>
#include <stdint.h>

#define N_NODES 50000
#define IN_CH   128
#define HID     128
#define OUT_CH  64

#define SCAN_B 256
#define SCAN_NB ((N_NODES + SCAN_B - 1) / SCAN_B)   // 196

// ---------------- degree / normalization / CSR build ----------------

__global__ void deg_zero_kernel(int* __restrict__ degi) {
    int i = blockIdx.x * 256 + threadIdx.x;
    if (i < N_NODES) degi[i] = 0;
}

__global__ void deg_count_kernel(const int* __restrict__ dst, int* __restrict__ degi, int E) {
    int e = blockIdx.x * 256 + threadIdx.x;
    if (e < E) {
        int d = dst[e];
        if ((unsigned)d < N_NODES) atomicAdd(&degi[d], 1);
    }
}

// s1: per-block sums of degi
__global__ __launch_bounds__(SCAN_B) void scan_s1_kernel(
    const int* __restrict__ degi, int* __restrict__ bsum) {
    __shared__ int sd[SCAN_B];
    int t = threadIdx.x;
    int i = blockIdx.x * SCAN_B + t;
    sd[t] = (i < N_NODES) ? degi[i] : 0;
    __syncthreads();
    #pragma unroll
    for (int off = SCAN_B / 2; off > 0; off >>= 1) {
        if (t < off) sd[t] += sd[t + off];
        __syncthreads();
    }
    if (t == 0) bsum[blockIdx.x] = sd[0];
}

// s2: exclusive scan of the 196 block sums (single block)
__global__ __launch_bounds__(SCAN_B) void scan_s2_kernel(
    const int* __restrict__ bsum, int* __restrict__ boffs) {
    __shared__ int sd[SCAN_B];
    int t = threadIdx.x;
    int v = (t < SCAN_NB) ? bsum[t] : 0;
    sd[t] = v;
    __syncthreads();
    #pragma unroll
    for (int off = 1; off < SCAN_B; off <<= 1) {
        int u = (t >= off) ? sd[t - off] : 0;
        __syncthreads();
        sd[t] += u;
        __syncthreads();
    }
    if (t < SCAN_NB) boffs[t] = sd[t] - v;   // exclusive
}

// s3: per-block exclusive scan + block offset -> offs/cursor; also dinv
__global__ __launch_bounds__(SCAN_B) void scan_s3_kernel(
    const int* __restrict__ degi, const int* __restrict__ boffs,
    int* __restrict__ offs, int* __restrict__ cursor, float* __restrict__ dinv) {
    __shared__ int sd[SCAN_B];
    int t = threadIdx.x;
    int i = blockIdx.x * SCAN_B + t;
    int v = (i < N_NODES) ? degi[i] : 0;
    sd[t] = v;
    __syncthreads();
    #pragma unroll
    for (int off = 1; off < SCAN_B; off <<= 1) {
        int u = (t >= off) ? sd[t - off] : 0;
        __syncthreads();
        sd[t] += u;
        __syncthreads();
    }
    if (i < N_NODES) {
        int excl = sd[t] - v + boffs[blockIdx.x];
        offs[i] = excl;
        cursor[i] = excl;
        dinv[i] = rsqrtf(1.0f + (float)v);
    }
}

__global__ void bucket_fill_kernel(const int* __restrict__ src, const int* __restrict__ dst,
                                   int* __restrict__ cursor, int* __restrict__ ebuf, int E) {
    int e = blockIdx.x * 256 + threadIdx.x;
    if (e < E) {
        int d = dst[e], s = src[e];
        if ((unsigned)d < N_NODES && (unsigned)s < N_NODES) {
            int pos = atomicAdd(&cursor[d], 1);
            ebuf[pos] = s;
        }
    }
}

// ---------------- GEMM1: h1 = x @ W1 ----------------
__global__ __launch_bounds__(256) void gemm1_kernel(
    const float* __restrict__ x, const float* __restrict__ W1,
    float* __restrict__ h1) {
    __shared__ float xs[16][IN_CH];
    const int block_row = blockIdx.x * 16;
    const int tid = threadIdx.x;

    const float4* xg = (const float4*)(x + (size_t)block_row * IN_CH);
    float4* xs4 = (float4*)(&xs[0][0]);
    #pragma unroll
    for (int i = 0; i < 2; ++i) xs4[tid + 256 * i] = xg[tid + 256 * i];
    __syncthreads();

    const int col = tid & 127;
    const int rg  = tid >> 7;
    float acc[8];
    #pragma unroll
    for (int r = 0; r < 8; ++r) acc[r] = 0.0f;

    #pragma unroll 4
    for (int k = 0; k < IN_CH; ++k) {
        float w = W1[k * HID + col];
        #pragma unroll
        for (int r = 0; r < 8; ++r) acc[r] += xs[rg + 2 * r][k] * w;
    }

    #pragma unroll
    for (int r = 0; r < 8; ++r) {
        int row = block_row + rg + 2 * r;
        h1[(size_t)row * HID + col] = acc[r];
    }
}

// ---------------- gather layer 1 ----------------
__global__ __launch_bounds__(256) void gather1_kernel(
    const int* __restrict__ offs, const int* __restrict__ degi,
    const int* __restrict__ ebuf, const float* __restrict__ dinv,
    const float* __restrict__ h1, float* __restrict__ agg1) {
    int node = blockIdx.x * 4 + (threadIdx.x >> 6);
    int lane = threadIdx.x & 63;
    if (node >= N_NODES) return;
    float di = dinv[node];
    int beg = offs[node];
    int cnt = degi[node];

    float2 self = ((const float2*)(h1 + (size_t)node * HID))[lane];
    float ax = self.x * di * di;
    float ay = self.y * di * di;

    int i = 0;
    for (; i + 2 <= cnt; i += 2) {
        int s0 = ebuf[beg + i], s1 = ebuf[beg + i + 1];
        float w0 = dinv[s0] * di, w1 = dinv[s1] * di;
        float2 v0 = ((const float2*)(h1 + (size_t)s0 * HID))[lane];
        float2 v1 = ((const float2*)(h1 + (size_t)s1 * HID))[lane];
        ax += v0.x * w0 + v1.x * w1;
        ay += v0.y * w0 + v1.y * w1;
    }
    if (i < cnt) {
        int s0 = ebuf[beg + i];
        float w0 = dinv[s0] * di;
        float2 v0 = ((const float2*)(h1 + (size_t)s0 * HID))[lane];
        ax += v0.x * w0;
        ay += v0.y * w0;
    }
    float2 r; r.x = ax; r.y = ay;
    ((float2*)(agg1 + (size_t)node * HID))[lane] = r;
}

// ---------------- GEMM2 ----------------
__global__ __launch_bounds__(256) void gemm2_kernel(
    const float* __restrict__ agg1, const float* __restrict__ b1,
    const float* __restrict__ W2, float* __restrict__ h2) {
    __shared__ float as_[16][HID];
    const int block_row = blockIdx.x * 16;
    const int tid = threadIdx.x;

    #pragma unroll
    for (int i = 0; i < 8; ++i) {
        int idx = tid + 256 * i;
        int r = idx >> 7, c = idx & 127;
        as_[r][c] = tanhf(agg1[(size_t)(block_row + r) * HID + c] + b1[c]);
    }
    __syncthreads();

    const int col = tid & 63;
    const int rg  = tid >> 6;
    float acc[4];
    #pragma unroll
    for (int r = 0; r < 4; ++r) acc[r] = 0.0f;

    #pragma unroll 4
    for (int k = 0; k < HID; ++k) {
        float w = W2[k * OUT_CH + col];
        #pragma unroll
        for (int r = 0; r < 4; ++r) acc[r] += as_[rg + 4 * r][k] * w;
    }

    #pragma unroll
    for (int r = 0; r < 4; ++r) {
        int row = block_row + rg + 4 * r;
        h2[(size_t)row * OUT_CH + col] = acc[r];
    }
}

// ---------------- gather layer 2 ----------------
__global__ __launch_bounds__(256) void gather2_kernel(
    const int* __restrict__ offs, const int* __restrict__ degi,
    const int* __restrict__ ebuf, const float* __restrict__ dinv,
    const float* __restrict__ h2, const float* __restrict__ b2,
    float* __restrict__ out) {
    int node = blockIdx.x * 4 + (threadIdx.x >> 6);
    int lane = threadIdx.x & 63;
    if (node >= N_NODES) return;
    float di = dinv[node];
    int beg = offs[node];
    int cnt = degi[node];

    float acc = b2[lane] + h2[(size_t)node * OUT_CH + lane] * di * di;

    int i = 0;
    for (; i + 2 <= cnt; i += 2) {
        int s0 = ebuf[beg + i], s1 = ebuf[beg + i + 1];
        float w0 = dinv[s0] * di, w1 = dinv[s1] * di;
        float v0 = h2[(size_t)s0 * OUT_CH + lane];
        float v1 = h2[(size_t)s1 * OUT_CH + lane];
        acc += v0 * w0 + v1 * w1;
    }
    if (i < cnt) {
        int s0 = ebuf[beg + i];
        float w0 = dinv[s0] * di;
        acc += h2[(size_t)s0 * OUT_CH + lane] * w0;
    }
    out[(size_t)node * OUT_CH + lane] = acc;
}

extern "C" void kernel_launch(void* const* d_in, const int* in_sizes, int n_in,
                              void* d_out, int out_size, void* d_ws, size_t ws_size,
                              hipStream_t stream) {
    const float* x  = (const float*)d_in[0];
    const int*   ei = (const int*)d_in[1];
    const float* W1 = (const float*)d_in[2];
    const float* b1 = (const float*)d_in[3];
    const float* W2 = (const float*)d_in[4];
    const float* b2 = (const float*)d_in[5];
    float* out = (float*)d_out;

    const int E = in_sizes[1] / 2;   // edge_index is [2, E]
    const int* src = ei;
    const int* dst = ei + E;

    // workspace layout
    float* dinv  = (float*)d_ws;               // N
    int* degi    = (int*)(dinv + N_NODES);     // N
    int* offs    = degi + N_NODES;             // N
    int* cursor  = offs + N_NODES;             // N
    int* bsum    = cursor + N_NODES;           // SCAN_NB
    int* boffs   = bsum + SCAN_NB;             // SCAN_NB
    int* ebuf    = boffs + SCAN_NB;            // E
    uintptr_t p  = (uintptr_t)(ebuf + E);
    p = (p + 15) & ~(uintptr_t)15;
    float* bufA  = (float*)p;                    // N*128 : h1, then h2
    float* bufB  = bufA + (size_t)N_NODES * HID; // N*128 : agg1
    float* h1 = bufA;
    float* agg1 = bufB;
    float* h2 = bufA;

    const int nblk_nodes = (N_NODES + 255) / 256;
    const int nblk_edges = (E + 255) / 256;

    deg_zero_kernel<<<nblk_nodes, 256, 0, stream>>>(degi);
    deg_count_kernel<<<nblk_edges, 256, 0, stream>>>(dst, degi, E);
    scan_s1_kernel<<<SCAN_NB, SCAN_B, 0, stream>>>(degi, bsum);
    scan_s2_kernel<<<1, SCAN_B, 0, stream>>>(bsum, boffs);
    scan_s3_kernel<<<SCAN_NB, SCAN_B, 0, stream>>>(degi, boffs, offs, cursor, dinv);
    bucket_fill_kernel<<<nblk_edges, 256, 0, stream>>>(src, dst, cursor, ebuf, E);

    gemm1_kernel<<<N_NODES / 16, 256, 0, stream>>>(x, W1, h1);
    gather1_kernel<<<(N_NODES + 3) / 4, 256, 0, stream>>>(offs, degi, ebuf, dinv, h1, agg1);
    gemm2_kernel<<<N_NODES / 16, 256, 0, stream>>>(agg1, b1, W2, h2);
    gather2_kernel<<<(N_NODES + 3) / 4, 256, 0, stream>>>(offs, degi, ebuf, dinv, h2, b2, out);
}

// Round 4
// 250.235 us; speedup vs baseline: 3.8013x; 1.1788x over previous
//
#include <hip/hip_runtime.h>
#include <stdint.h>

#define N_NODES 50000
#define IN_CH   128
#define HID     128
#define OUT_CH  64

#define SCAN_B 256
#define SCAN_NB ((N_NODES + SCAN_B - 1) / SCAN_B)   // 196

typedef unsigned int  uint32;
typedef unsigned short ushort16;

static __device__ __forceinline__ ushort16 f32_to_bf16(float f) {
    uint32 u = __float_as_uint(f);
    u = (u + 0x7fffu + ((u >> 16) & 1u)) >> 16;   // RNE
    return (ushort16)u;
}
static __device__ __forceinline__ float bf16lo_to_f32(uint32 u) {
    return __uint_as_float(u << 16);
}
static __device__ __forceinline__ float bf16hi_to_f32(uint32 u) {
    return __uint_as_float(u & 0xffff0000u);
}

// ---------------- degree / normalization / CSR build ----------------

__global__ void deg_zero_kernel(int* __restrict__ degi) {
    int i = blockIdx.x * 256 + threadIdx.x;
    if (i < N_NODES) degi[i] = 0;
}

__global__ void deg_count_kernel(const int* __restrict__ dst, int* __restrict__ degi, int E) {
    int e = blockIdx.x * 256 + threadIdx.x;
    if (e < E) {
        int d = dst[e];
        if ((unsigned)d < N_NODES) atomicAdd(&degi[d], 1);
    }
}

// s1: per-block sums of degi
__global__ __launch_bounds__(SCAN_B) void scan_s1_kernel(
    const int* __restrict__ degi, int* __restrict__ bsum) {
    __shared__ int sd[SCAN_B];
    int t = threadIdx.x;
    int i = blockIdx.x * SCAN_B + t;
    sd[t] = (i < N_NODES) ? degi[i] : 0;
    __syncthreads();
    #pragma unroll
    for (int off = SCAN_B / 2; off > 0; off >>= 1) {
        if (t < off) sd[t] += sd[t + off];
        __syncthreads();
    }
    if (t == 0) bsum[blockIdx.x] = sd[0];
}

// s2: exclusive scan of the 196 block sums (single block)
__global__ __launch_bounds__(SCAN_B) void scan_s2_kernel(
    const int* __restrict__ bsum, int* __restrict__ boffs) {
    __shared__ int sd[SCAN_B];
    int t = threadIdx.x;
    int v = (t < SCAN_NB) ? bsum[t] : 0;
    sd[t] = v;
    __syncthreads();
    #pragma unroll
    for (int off = 1; off < SCAN_B; off <<= 1) {
        int u = (t >= off) ? sd[t - off] : 0;
        __syncthreads();
        sd[t] += u;
        __syncthreads();
    }
    if (t < SCAN_NB) boffs[t] = sd[t] - v;   // exclusive
}

// s3: per-block exclusive scan + block offset -> offs/cursor; also dinv
__global__ __launch_bounds__(SCAN_B) void scan_s3_kernel(
    const int* __restrict__ degi, const int* __restrict__ boffs,
    int* __restrict__ offs, int* __restrict__ cursor, float* __restrict__ dinv) {
    __shared__ int sd[SCAN_B];
    int t = threadIdx.x;
    int i = blockIdx.x * SCAN_B + t;
    int v = (i < N_NODES) ? degi[i] : 0;
    sd[t] = v;
    __syncthreads();
    #pragma unroll
    for (int off = 1; off < SCAN_B; off <<= 1) {
        int u = (t >= off) ? sd[t - off] : 0;
        __syncthreads();
        sd[t] += u;
        __syncthreads();
    }
    if (i < N_NODES) {
        int excl = sd[t] - v + boffs[blockIdx.x];
        offs[i] = excl;
        cursor[i] = excl;
        dinv[i] = rsqrtf(1.0f + (float)v);
    }
}

__global__ void bucket_fill_kernel(const int* __restrict__ src, const int* __restrict__ dst,
                                   int* __restrict__ cursor, int* __restrict__ ebuf, int E) {
    int e = blockIdx.x * 256 + threadIdx.x;
    if (e < E) {
        int d = dst[e], s = src[e];
        if ((unsigned)d < N_NODES && (unsigned)s < N_NODES) {
            int pos = atomicAdd(&cursor[d], 1);
            ebuf[pos] = s;
        }
    }
}

// ---------------- GEMM1: h1 = bf16(x @ W1) ----------------
__global__ __launch_bounds__(256) void gemm1_kernel(
    const float* __restrict__ x, const float* __restrict__ W1,
    ushort16* __restrict__ h1b) {
    __shared__ float xs[16][IN_CH];
    const int block_row = blockIdx.x * 16;
    const int tid = threadIdx.x;

    const float4* xg = (const float4*)(x + (size_t)block_row * IN_CH);
    float4* xs4 = (float4*)(&xs[0][0]);
    #pragma unroll
    for (int i = 0; i < 2; ++i) xs4[tid + 256 * i] = xg[tid + 256 * i];
    __syncthreads();

    const int col = tid & 127;
    const int rg  = tid >> 7;
    float acc[8];
    #pragma unroll
    for (int r = 0; r < 8; ++r) acc[r] = 0.0f;

    #pragma unroll 4
    for (int k = 0; k < IN_CH; ++k) {
        float w = W1[k * HID + col];
        #pragma unroll
        for (int r = 0; r < 8; ++r) acc[r] += xs[rg + 2 * r][k] * w;
    }

    #pragma unroll
    for (int r = 0; r < 8; ++r) {
        int row = block_row + rg + 2 * r;
        h1b[(size_t)row * HID + col] = f32_to_bf16(acc[r]);
    }
}

// ---------------- gather layer 1: agg1 = D^-1/2 A D^-1/2 h1 (+self) ----------------
// one wave per node; lane handles 2 bf16 columns (one uint32 load per row)
__global__ __launch_bounds__(256) void gather1_kernel(
    const int* __restrict__ offs, const int* __restrict__ degi,
    const int* __restrict__ ebuf, const float* __restrict__ dinv,
    const ushort16* __restrict__ h1b, float* __restrict__ agg1) {
    int node = blockIdx.x * 4 + (threadIdx.x >> 6);
    int lane = threadIdx.x & 63;
    if (node >= N_NODES) return;
    float di = dinv[node];
    int beg = offs[node];
    int cnt = degi[node];

    uint32 us = ((const uint32*)(h1b + (size_t)node * HID))[lane];
    float ax = bf16lo_to_f32(us) * di * di;
    float ay = bf16hi_to_f32(us) * di * di;

    int i = 0;
    for (; i + 4 <= cnt; i += 4) {
        int s0 = ebuf[beg + i], s1 = ebuf[beg + i + 1];
        int s2 = ebuf[beg + i + 2], s3 = ebuf[beg + i + 3];
        float w0 = dinv[s0] * di, w1 = dinv[s1] * di;
        float w2 = dinv[s2] * di, w3 = dinv[s3] * di;
        uint32 u0 = ((const uint32*)(h1b + (size_t)s0 * HID))[lane];
        uint32 u1 = ((const uint32*)(h1b + (size_t)s1 * HID))[lane];
        uint32 u2 = ((const uint32*)(h1b + (size_t)s2 * HID))[lane];
        uint32 u3 = ((const uint32*)(h1b + (size_t)s3 * HID))[lane];
        ax += bf16lo_to_f32(u0) * w0 + bf16lo_to_f32(u1) * w1
            + bf16lo_to_f32(u2) * w2 + bf16lo_to_f32(u3) * w3;
        ay += bf16hi_to_f32(u0) * w0 + bf16hi_to_f32(u1) * w1
            + bf16hi_to_f32(u2) * w2 + bf16hi_to_f32(u3) * w3;
    }
    for (; i < cnt; ++i) {
        int s0 = ebuf[beg + i];
        float w0 = dinv[s0] * di;
        uint32 u0 = ((const uint32*)(h1b + (size_t)s0 * HID))[lane];
        ax += bf16lo_to_f32(u0) * w0;
        ay += bf16hi_to_f32(u0) * w0;
    }
    float2 r; r.x = ax; r.y = ay;
    ((float2*)(agg1 + (size_t)node * HID))[lane] = r;
}

// ---------------- GEMM2: a1 = tanh(agg1 + b1); h2 = bf16(a1 @ W2) ----------------
__global__ __launch_bounds__(256) void gemm2_kernel(
    const float* __restrict__ agg1, const float* __restrict__ b1,
    const float* __restrict__ W2, ushort16* __restrict__ h2b) {
    __shared__ float as_[16][HID];
    const int block_row = blockIdx.x * 16;
    const int tid = threadIdx.x;

    #pragma unroll
    for (int i = 0; i < 8; ++i) {
        int idx = tid + 256 * i;
        int r = idx >> 7, c = idx & 127;
        as_[r][c] = tanhf(agg1[(size_t)(block_row + r) * HID + c] + b1[c]);
    }
    __syncthreads();

    const int col = tid & 63;
    const int rg  = tid >> 6;
    float acc[4];
    #pragma unroll
    for (int r = 0; r < 4; ++r) acc[r] = 0.0f;

    #pragma unroll 4
    for (int k = 0; k < HID; ++k) {
        float w = W2[k * OUT_CH + col];
        #pragma unroll
        for (int r = 0; r < 4; ++r) acc[r] += as_[rg + 4 * r][k] * w;
    }

    #pragma unroll
    for (int r = 0; r < 4; ++r) {
        int row = block_row + rg + 4 * r;
        h2b[(size_t)row * OUT_CH + col] = f32_to_bf16(acc[r]);
    }
}

// ---------------- gather layer 2: out = b2 + D^-1/2 A D^-1/2 h2 (+self) ----------------
// one wave per node; lane per column (64), bf16 ushort loads
__global__ __launch_bounds__(256) void gather2_kernel(
    const int* __restrict__ offs, const int* __restrict__ degi,
    const int* __restrict__ ebuf, const float* __restrict__ dinv,
    const ushort16* __restrict__ h2b, const float* __restrict__ b2,
    float* __restrict__ out) {
    int node = blockIdx.x * 4 + (threadIdx.x >> 6);
    int lane = threadIdx.x & 63;
    if (node >= N_NODES) return;
    float di = dinv[node];
    int beg = offs[node];
    int cnt = degi[node];

    float self = __uint_as_float(((uint32)h2b[(size_t)node * OUT_CH + lane]) << 16);
    float acc = b2[lane] + self * di * di;

    int i = 0;
    for (; i + 4 <= cnt; i += 4) {
        int s0 = ebuf[beg + i], s1 = ebuf[beg + i + 1];
        int s2 = ebuf[beg + i + 2], s3 = ebuf[beg + i + 3];
        float w0 = dinv[s0] * di, w1 = dinv[s1] * di;
        float w2 = dinv[s2] * di, w3 = dinv[s3] * di;
        float v0 = __uint_as_float(((uint32)h2b[(size_t)s0 * OUT_CH + lane]) << 16);
        float v1 = __uint_as_float(((uint32)h2b[(size_t)s1 * OUT_CH + lane]) << 16);
        float v2 = __uint_as_float(((uint32)h2b[(size_t)s2 * OUT_CH + lane]) << 16);
        float v3 = __uint_as_float(((uint32)h2b[(size_t)s3 * OUT_CH + lane]) << 16);
        acc += v0 * w0 + v1 * w1 + v2 * w2 + v3 * w3;
    }
    for (; i < cnt; ++i) {
        int s0 = ebuf[beg + i];
        float w0 = dinv[s0] * di;
        float v0 = __uint_as_float(((uint32)h2b[(size_t)s0 * OUT_CH + lane]) << 16);
        acc += v0 * w0;
    }
    out[(size_t)node * OUT_CH + lane] = acc;
}

extern "C" void kernel_launch(void* const* d_in, const int* in_sizes, int n_in,
                              void* d_out, int out_size, void* d_ws, size_t ws_size,
                              hipStream_t stream) {
    const float* x  = (const float*)d_in[0];
    const int*   ei = (const int*)d_in[1];
    const float* W1 = (const float*)d_in[2];
    const float* b1 = (const float*)d_in[3];
    const float* W2 = (const float*)d_in[4];
    const float* b2 = (const float*)d_in[5];
    float* out = (float*)d_out;

    const int E = in_sizes[1] / 2;   // edge_index is [2, E]
    const int* src = ei;
    const int* dst = ei + E;

    // workspace layout
    float* dinv  = (float*)d_ws;               // N
    int* degi    = (int*)(dinv + N_NODES);     // N
    int* offs    = degi + N_NODES;             // N
    int* cursor  = offs + N_NODES;             // N
    int* bsum    = cursor + N_NODES;           // SCAN_NB
    int* boffs   = bsum + SCAN_NB;             // SCAN_NB
    int* ebuf    = boffs + SCAN_NB;            // E
    uintptr_t p  = (uintptr_t)(ebuf + E);
    p = (p + 15) & ~(uintptr_t)15;
    float* agg1  = (float*)p;                       // N*128 f32
    ushort16* h1b = (ushort16*)(agg1 + (size_t)N_NODES * HID);  // N*128 bf16
    ushort16* h2b = h1b + (size_t)N_NODES * HID;                // N*64 bf16

    const int nblk_nodes = (N_NODES + 255) / 256;
    const int nblk_edges = (E + 255) / 256;

    deg_zero_kernel<<<nblk_nodes, 256, 0, stream>>>(degi);
    deg_count_kernel<<<nblk_edges, 256, 0, stream>>>(dst, degi, E);
    scan_s1_kernel<<<SCAN_NB, SCAN_B, 0, stream>>>(degi, bsum);
    scan_s2_kernel<<<1, SCAN_B, 0, stream>>>(bsum, boffs);
    scan_s3_kernel<<<SCAN_NB, SCAN_B, 0, stream>>>(degi, boffs, offs, cursor, dinv);
    bucket_fill_kernel<<<nblk_edges, 256, 0, stream>>>(src, dst, cursor, ebuf, E);

    gemm1_kernel<<<N_NODES / 16, 256, 0, stream>>>(x, W1, h1b);
    gather1_kernel<<<(N_NODES + 3) / 4, 256, 0, stream>>>(offs, degi, ebuf, dinv, h1b, agg1);
    gemm2_kernel<<<N_NODES / 16, 256, 0, stream>>>(agg1, b1, W2, h2b);
    gather2_kernel<<<(N_NODES + 3) / 4, 256, 0, stream>>>(offs, degi, ebuf, dinv, h2b, b2, out);
}

// Round 5
// 178.536 us; speedup vs baseline: 5.3279x; 1.4016x over previous
//
#include <hip/hip_runtime.h>
#include <stdint.h>

#define N_NODES 50000
#define IN_CH   128
#define HID     128
#define OUT_CH  64

#define CBITS 8
#define NCB   ((N_NODES + 255) >> 8)     // 196 coarse buckets (dst>>8)
#define CAP   8192                        // per-bucket capacity in ebuf2
#define APB   4096                        // edges per pass-A block

typedef unsigned int   uint32;
typedef unsigned short ushort16;

static __device__ __forceinline__ ushort16 f32_to_bf16(float f) {
    uint32 u = __float_as_uint(f);
    u = (u + 0x7fffu + ((u >> 16) & 1u)) >> 16;   // RNE
    return (ushort16)u;
}
static __device__ __forceinline__ float bf16lo_to_f32(uint32 u) {
    return __uint_as_float(u << 16);
}
static __device__ __forceinline__ float bf16hi_to_f32(uint32 u) {
    return __uint_as_float(u & 0xffff0000u);
}

// ---------------- CSR build: two-level LDS radix sort by dst ----------------

__global__ void curinit_kernel(int* __restrict__ gcur) {
    int t = threadIdx.x;
    if (t < NCB) gcur[t] = t * CAP;
}

// Pass A: coarse partition edges by dst>>8 into ebuf2 (entries: src | dst<<16)
__global__ __launch_bounds__(256) void passA_kernel(
    const int* __restrict__ src, const int* __restrict__ dst,
    int* __restrict__ gcur, uint32* __restrict__ ebuf2, int E) {
    __shared__ int hist[256];
    __shared__ int excl[256];
    __shared__ int fcur[256];
    __shared__ int gbase[256];
    __shared__ uint32 obuf[APB];
    const int t = threadIdx.x;
    const int e0 = blockIdx.x * APB;
    const int nv = min(APB, E - e0);

    hist[t] = 0;
    __syncthreads();

    uint32 u[16];
    #pragma unroll
    for (int j = 0; j < 16; ++j) {
        int i = t + 256 * j;
        u[j] = 0xffffffffu;
        if (i < nv) {
            int e = e0 + i;
            int s = src[e], d = dst[e];
            if ((unsigned)d < N_NODES && (unsigned)s < N_NODES) {
                u[j] = (uint32)s | ((uint32)d << 16);
                atomicAdd(&hist[(unsigned)d >> CBITS], 1);
            }
        }
    }
    __syncthreads();

    // inclusive scan of hist -> excl, then make exclusive
    excl[t] = hist[t];
    __syncthreads();
    #pragma unroll
    for (int off = 1; off < 256; off <<= 1) {
        int v = (t >= off) ? excl[t - off] : 0;
        __syncthreads();
        excl[t] += v;
        __syncthreads();
    }
    int myexcl = excl[t] - hist[t];
    if (hist[t] > 0) gbase[t] = atomicAdd(&gcur[t], hist[t]);
    __syncthreads();           // excl[] reads done above; now safe to overwrite
    excl[t] = myexcl;
    fcur[t] = myexcl;
    __syncthreads();

    #pragma unroll
    for (int j = 0; j < 16; ++j) {
        if (u[j] != 0xffffffffu) {
            int b = u[j] >> (16 + CBITS);
            int pos = atomicAdd(&fcur[b], 1);
            obuf[pos] = u[j];
        }
    }
    __syncthreads();

    for (int i = t; i < nv; i += 256) {
        uint32 v = obuf[i];
        int b = v >> (16 + CBITS);
        int gpos = gbase[b] + (i - excl[b]);
        if (gpos < (b + 1) * CAP) ebuf2[gpos] = v;   // capacity guard
    }
}

// Interlude: per-bucket counts + exclusive scan -> global edge offsets
__global__ __launch_bounds__(256) void interlude_kernel(
    const int* __restrict__ gcur, int* __restrict__ ecnt, int* __restrict__ eoff) {
    __shared__ int sd[256];
    int t = threadIdx.x;
    int c = (t < NCB) ? (gcur[t] - t * CAP) : 0;
    sd[t] = c;
    __syncthreads();
    #pragma unroll
    for (int off = 1; off < 256; off <<= 1) {
        int v = (t >= off) ? sd[t - off] : 0;
        __syncthreads();
        sd[t] += v;
        __syncthreads();
    }
    if (t < NCB) { ecnt[t] = c; eoff[t] = sd[t] - c; }
}

// Pass B: fine sort within bucket by node; emit u16 src list + degi/offs/dinv
__global__ __launch_bounds__(256) void passB_kernel(
    const uint32* __restrict__ ebuf2, const int* __restrict__ ecnt,
    const int* __restrict__ eoff, ushort16* __restrict__ ebuf16,
    int* __restrict__ offs, int* __restrict__ degi, float* __restrict__ dinv) {
    __shared__ uint32 sbuf[CAP];
    __shared__ ushort16 obuf[CAP];
    __shared__ int fh[256];
    __shared__ int fx[256];
    __shared__ int fc[256];
    const int b = blockIdx.x, t = threadIdx.x;
    const int nb = ecnt[b];
    const int base = b * CAP;
    const int obase = eoff[b];

    fh[t] = 0;
    __syncthreads();
    for (int i = t; i < nb; i += 256) {
        uint32 v = ebuf2[base + i];
        sbuf[i] = v;
        atomicAdd(&fh[(v >> 16) & 255], 1);
    }
    __syncthreads();

    fx[t] = fh[t];
    __syncthreads();
    #pragma unroll
    for (int off = 1; off < 256; off <<= 1) {
        int v = (t >= off) ? fx[t - off] : 0;
        __syncthreads();
        fx[t] += v;
        __syncthreads();
    }
    int ex = fx[t] - fh[t];
    fc[t] = ex;

    int n = b * 256 + t;
    if (n < N_NODES) {
        degi[n] = fh[t];
        offs[n] = obase + ex;
        dinv[n] = rsqrtf(1.0f + (float)fh[t]);
    }
    __syncthreads();

    for (int i = t; i < nb; i += 256) {
        uint32 v = sbuf[i];
        int nl = (v >> 16) & 255;
        int pos = atomicAdd(&fc[nl], 1);
        obuf[pos] = (ushort16)(v & 0xffffu);
    }
    __syncthreads();
    for (int i = t; i < nb; i += 256) ebuf16[obase + i] = obuf[i];
}

// ---------------- GEMM1: h1 = bf16(x @ W1) ----------------
__global__ __launch_bounds__(256) void gemm1_kernel(
    const float* __restrict__ x, const float* __restrict__ W1,
    ushort16* __restrict__ h1b) {
    __shared__ float xs[16][IN_CH];
    const int block_row = blockIdx.x * 16;
    const int tid = threadIdx.x;

    const float4* xg = (const float4*)(x + (size_t)block_row * IN_CH);
    float4* xs4 = (float4*)(&xs[0][0]);
    #pragma unroll
    for (int i = 0; i < 2; ++i) xs4[tid + 256 * i] = xg[tid + 256 * i];
    __syncthreads();

    const int col = tid & 127;
    const int rg  = tid >> 7;
    float acc[8];
    #pragma unroll
    for (int r = 0; r < 8; ++r) acc[r] = 0.0f;

    #pragma unroll 4
    for (int k = 0; k < IN_CH; ++k) {
        float w = W1[k * HID + col];
        #pragma unroll
        for (int r = 0; r < 8; ++r) acc[r] += xs[rg + 2 * r][k] * w;
    }

    #pragma unroll
    for (int r = 0; r < 8; ++r) {
        int row = block_row + rg + 2 * r;
        h1b[(size_t)row * HID + col] = f32_to_bf16(acc[r]);
    }
}

// ---------------- gather layer 1 ----------------
__global__ __launch_bounds__(256) void gather1_kernel(
    const int* __restrict__ offs, const int* __restrict__ degi,
    const ushort16* __restrict__ ebuf16, const float* __restrict__ dinv,
    const ushort16* __restrict__ h1b, float* __restrict__ agg1) {
    int node = blockIdx.x * 4 + (threadIdx.x >> 6);
    int lane = threadIdx.x & 63;
    if (node >= N_NODES) return;
    float di = dinv[node];
    int beg = offs[node];
    int cnt = degi[node];

    uint32 us = ((const uint32*)(h1b + (size_t)node * HID))[lane];
    float ax = bf16lo_to_f32(us) * di * di;
    float ay = bf16hi_to_f32(us) * di * di;

    int i = 0;
    for (; i + 4 <= cnt; i += 4) {
        int s0 = ebuf16[beg + i], s1 = ebuf16[beg + i + 1];
        int s2 = ebuf16[beg + i + 2], s3 = ebuf16[beg + i + 3];
        float w0 = dinv[s0] * di, w1 = dinv[s1] * di;
        float w2 = dinv[s2] * di, w3 = dinv[s3] * di;
        uint32 u0 = ((const uint32*)(h1b + (size_t)s0 * HID))[lane];
        uint32 u1 = ((const uint32*)(h1b + (size_t)s1 * HID))[lane];
        uint32 u2 = ((const uint32*)(h1b + (size_t)s2 * HID))[lane];
        uint32 u3 = ((const uint32*)(h1b + (size_t)s3 * HID))[lane];
        ax += bf16lo_to_f32(u0) * w0 + bf16lo_to_f32(u1) * w1
            + bf16lo_to_f32(u2) * w2 + bf16lo_to_f32(u3) * w3;
        ay += bf16hi_to_f32(u0) * w0 + bf16hi_to_f32(u1) * w1
            + bf16hi_to_f32(u2) * w2 + bf16hi_to_f32(u3) * w3;
    }
    for (; i < cnt; ++i) {
        int s0 = ebuf16[beg + i];
        float w0 = dinv[s0] * di;
        uint32 u0 = ((const uint32*)(h1b + (size_t)s0 * HID))[lane];
        ax += bf16lo_to_f32(u0) * w0;
        ay += bf16hi_to_f32(u0) * w0;
    }
    float2 r; r.x = ax; r.y = ay;
    ((float2*)(agg1 + (size_t)node * HID))[lane] = r;
}

// ---------------- GEMM2: a1 = tanh(agg1 + b1); h2 = bf16(a1 @ W2) ----------------
__global__ __launch_bounds__(256) void gemm2_kernel(
    const float* __restrict__ agg1, const float* __restrict__ b1,
    const float* __restrict__ W2, ushort16* __restrict__ h2b) {
    __shared__ float as_[16][HID];
    const int block_row = blockIdx.x * 16;
    const int tid = threadIdx.x;

    #pragma unroll
    for (int i = 0; i < 8; ++i) {
        int idx = tid + 256 * i;
        int r = idx >> 7, c = idx & 127;
        as_[r][c] = tanhf(agg1[(size_t)(block_row + r) * HID + c] + b1[c]);
    }
    __syncthreads();

    const int col = tid & 63;
    const int rg  = tid >> 6;
    float acc[4];
    #pragma unroll
    for (int r = 0; r < 4; ++r) acc[r] = 0.0f;

    #pragma unroll 4
    for (int k = 0; k < HID; ++k) {
        float w = W2[k * OUT_CH + col];
        #pragma unroll
        for (int r = 0; r < 4; ++r) acc[r] += as_[rg + 4 * r][k] * w;
    }

    #pragma unroll
    for (int r = 0; r < 4; ++r) {
        int row = block_row + rg + 4 * r;
        h2b[(size_t)row * OUT_CH + col] = f32_to_bf16(acc[r]);
    }
}

// ---------------- gather layer 2 ----------------
__global__ __launch_bounds__(256) void gather2_kernel(
    const int* __restrict__ offs, const int* __restrict__ degi,
    const ushort16* __restrict__ ebuf16, const float* __restrict__ dinv,
    const ushort16* __restrict__ h2b, const float* __restrict__ b2,
    float* __restrict__ out) {
    int node = blockIdx.x * 4 + (threadIdx.x >> 6);
    int lane = threadIdx.x & 63;
    if (node >= N_NODES) return;
    float di = dinv[node];
    int beg = offs[node];
    int cnt = degi[node];

    float self = __uint_as_float(((uint32)h2b[(size_t)node * OUT_CH + lane]) << 16);
    float acc = b2[lane] + self * di * di;

    int i = 0;
    for (; i + 4 <= cnt; i += 4) {
        int s0 = ebuf16[beg + i], s1 = ebuf16[beg + i + 1];
        int s2 = ebuf16[beg + i + 2], s3 = ebuf16[beg + i + 3];
        float w0 = dinv[s0] * di, w1 = dinv[s1] * di;
        float w2 = dinv[s2] * di, w3 = dinv[s3] * di;
        float v0 = __uint_as_float(((uint32)h2b[(size_t)s0 * OUT_CH + lane]) << 16);
        float v1 = __uint_as_float(((uint32)h2b[(size_t)s1 * OUT_CH + lane]) << 16);
        float v2 = __uint_as_float(((uint32)h2b[(size_t)s2 * OUT_CH + lane]) << 16);
        float v3 = __uint_as_float(((uint32)h2b[(size_t)s3 * OUT_CH + lane]) << 16);
        acc += v0 * w0 + v1 * w1 + v2 * w2 + v3 * w3;
    }
    for (; i < cnt; ++i) {
        int s0 = ebuf16[beg + i];
        float w0 = dinv[s0] * di;
        float v0 = __uint_as_float(((uint32)h2b[(size_t)s0 * OUT_CH + lane]) << 16);
        acc += v0 * w0;
    }
    out[(size_t)node * OUT_CH + lane] = acc;
}

extern "C" void kernel_launch(void* const* d_in, const int* in_sizes, int n_in,
                              void* d_out, int out_size, void* d_ws, size_t ws_size,
                              hipStream_t stream) {
    const float* x  = (const float*)d_in[0];
    const int*   ei = (const int*)d_in[1];
    const float* W1 = (const float*)d_in[2];
    const float* b1 = (const float*)d_in[3];
    const float* W2 = (const float*)d_in[4];
    const float* b2 = (const float*)d_in[5];
    float* out = (float*)d_out;

    const int E = in_sizes[1] / 2;   // edge_index is [2, E]
    const int* src = ei;
    const int* dst = ei + E;

    // workspace layout
    float* dinv   = (float*)d_ws;                 // N
    int* degi     = (int*)(dinv + N_NODES);       // N
    int* offs     = degi + N_NODES;               // N
    int* gcur     = offs + N_NODES;               // NCB
    int* ecnt     = gcur + NCB;                   // NCB
    int* eoff     = ecnt + NCB;                   // NCB
    ushort16* ebuf16 = (ushort16*)(eoff + NCB);   // E (u16)
    uintptr_t p   = (uintptr_t)(ebuf16 + E);
    p = (p + 15) & ~(uintptr_t)15;
    float* agg1   = (float*)p;                        // N*128 f32
    uint32* ebuf2 = (uint32*)agg1;                    // NCB*CAP u32, aliases agg1 (used before it)
    ushort16* h1b = (ushort16*)(agg1 + (size_t)N_NODES * HID);  // N*128 bf16
    ushort16* h2b = h1b + (size_t)N_NODES * HID;                // N*64 bf16

    curinit_kernel<<<1, 256, 0, stream>>>(gcur);
    passA_kernel<<<(E + APB - 1) / APB, 256, 0, stream>>>(src, dst, gcur, ebuf2, E);
    interlude_kernel<<<1, 256, 0, stream>>>(gcur, ecnt, eoff);
    passB_kernel<<<NCB, 256, 0, stream>>>(ebuf2, ecnt, eoff, ebuf16, offs, degi, dinv);

    gemm1_kernel<<<N_NODES / 16, 256, 0, stream>>>(x, W1, h1b);
    gather1_kernel<<<(N_NODES + 3) / 4, 256, 0, stream>>>(offs, degi, ebuf16, dinv, h1b, agg1);
    gemm2_kernel<<<N_NODES / 16, 256, 0, stream>>>(agg1, b1, W2, h2b);
    gather2_kernel<<<(N_NODES + 3) / 4, 256, 0, stream>>>(offs, degi, ebuf16, dinv, h2b, b2, out);
}

// Round 6
// 129.157 us; speedup vs baseline: 7.3648x; 1.3823x over previous
//
#include <hip/hip_runtime.h>
#include <stdint.h>

#define N_NODES 50000
#define IN_CH   128
#define HID     128
#define OUT_CH  64

#define CBITS 8
#define NCB   ((N_NODES + 255) >> 8)     // 196 coarse buckets (dst>>8)
#define CAP   8192                        // per-bucket capacity in ebuf2
#define APB   4096                        // edges per pass-A block

#define XPAD  136                         // ushorts per LDS row (128 + 8 pad)

typedef unsigned int   uint32;
typedef unsigned short ushort16;
typedef __attribute__((ext_vector_type(8))) short short8;   // 8 bf16
typedef __attribute__((ext_vector_type(4))) float f32x4;

static __device__ __forceinline__ ushort16 f32_to_bf16(float f) {
    uint32 u = __float_as_uint(f);
    u = (u + 0x7fffu + ((u >> 16) & 1u)) >> 16;   // RNE
    return (ushort16)u;
}
static __device__ __forceinline__ float bf16lo_to_f32(uint32 u) {
    return __uint_as_float(u << 16);
}
static __device__ __forceinline__ float bf16hi_to_f32(uint32 u) {
    return __uint_as_float(u & 0xffff0000u);
}

// ---------------- CSR build: two-level LDS radix sort by dst ----------------

__global__ void curinit_kernel(int* __restrict__ gcur) {
    int t = threadIdx.x;
    if (t < NCB) gcur[t] = t * CAP;
}

__global__ __launch_bounds__(256) void passA_kernel(
    const int* __restrict__ src, const int* __restrict__ dst,
    int* __restrict__ gcur, uint32* __restrict__ ebuf2, int E) {
    __shared__ int hist[256];
    __shared__ int excl[256];
    __shared__ int fcur[256];
    __shared__ int gbase[256];
    __shared__ uint32 obuf[APB];
    const int t = threadIdx.x;
    const int e0 = blockIdx.x * APB;
    const int nv = min(APB, E - e0);

    hist[t] = 0;
    __syncthreads();

    uint32 u[16];
    #pragma unroll
    for (int j = 0; j < 16; ++j) {
        int i = t + 256 * j;
        u[j] = 0xffffffffu;
        if (i < nv) {
            int e = e0 + i;
            int s = src[e], d = dst[e];
            if ((unsigned)d < N_NODES && (unsigned)s < N_NODES) {
                u[j] = (uint32)s | ((uint32)d << 16);
                atomicAdd(&hist[(unsigned)d >> CBITS], 1);
            }
        }
    }
    __syncthreads();

    excl[t] = hist[t];
    __syncthreads();
    #pragma unroll
    for (int off = 1; off < 256; off <<= 1) {
        int v = (t >= off) ? excl[t - off] : 0;
        __syncthreads();
        excl[t] += v;
        __syncthreads();
    }
    int myexcl = excl[t] - hist[t];
    if (hist[t] > 0) gbase[t] = atomicAdd(&gcur[t], hist[t]);
    __syncthreads();
    excl[t] = myexcl;
    fcur[t] = myexcl;
    __syncthreads();

    #pragma unroll
    for (int j = 0; j < 16; ++j) {
        if (u[j] != 0xffffffffu) {
            int b = u[j] >> (16 + CBITS);
            int pos = atomicAdd(&fcur[b], 1);
            obuf[pos] = u[j];
        }
    }
    __syncthreads();

    for (int i = t; i < nv; i += 256) {
        uint32 v = obuf[i];
        int b = v >> (16 + CBITS);
        int gpos = gbase[b] + (i - excl[b]);
        if (gpos < (b + 1) * CAP) ebuf2[gpos] = v;
    }
}

__global__ __launch_bounds__(256) void interlude_kernel(
    const int* __restrict__ gcur, int* __restrict__ ecnt, int* __restrict__ eoff) {
    __shared__ int sd[256];
    int t = threadIdx.x;
    int c = (t < NCB) ? (gcur[t] - t * CAP) : 0;
    sd[t] = c;
    __syncthreads();
    #pragma unroll
    for (int off = 1; off < 256; off <<= 1) {
        int v = (t >= off) ? sd[t - off] : 0;
        __syncthreads();
        sd[t] += v;
        __syncthreads();
    }
    if (t < NCB) { ecnt[t] = c; eoff[t] = sd[t] - c; }
}

__global__ __launch_bounds__(256) void passB_kernel(
    const uint32* __restrict__ ebuf2, const int* __restrict__ ecnt,
    const int* __restrict__ eoff, ushort16* __restrict__ ebuf16,
    int* __restrict__ offs, int* __restrict__ degi, float* __restrict__ dinv) {
    __shared__ uint32 sbuf[CAP];
    __shared__ ushort16 obuf[CAP];
    __shared__ int fh[256];
    __shared__ int fx[256];
    __shared__ int fc[256];
    const int b = blockIdx.x, t = threadIdx.x;
    const int nb = ecnt[b];
    const int base = b * CAP;
    const int obase = eoff[b];

    fh[t] = 0;
    __syncthreads();
    for (int i = t; i < nb; i += 256) {
        uint32 v = ebuf2[base + i];
        sbuf[i] = v;
        atomicAdd(&fh[(v >> 16) & 255], 1);
    }
    __syncthreads();

    fx[t] = fh[t];
    __syncthreads();
    #pragma unroll
    for (int off = 1; off < 256; off <<= 1) {
        int v = (t >= off) ? fx[t - off] : 0;
        __syncthreads();
        fx[t] += v;
        __syncthreads();
    }
    int ex = fx[t] - fh[t];
    fc[t] = ex;

    int n = b * 256 + t;
    if (n < N_NODES) {
        degi[n] = fh[t];
        offs[n] = obase + ex;
        dinv[n] = rsqrtf(1.0f + (float)fh[t]);
    }
    __syncthreads();

    for (int i = t; i < nb; i += 256) {
        uint32 v = sbuf[i];
        int nl = (v >> 16) & 255;
        int pos = atomicAdd(&fc[nl], 1);
        obuf[pos] = (ushort16)(v & 0xffffu);
    }
    __syncthreads();
    for (int i = t; i < nb; i += 256) ebuf16[obase + i] = obuf[i];
}

// ---------------- prep: W1^T, W2^T as bf16 [N][K] ----------------
__global__ __launch_bounds__(256) void prep_w_kernel(
    const float* __restrict__ W1, const float* __restrict__ W2,
    ushort16* __restrict__ w1t, ushort16* __restrict__ w2t) {
    int i = blockIdx.x * 256 + threadIdx.x;
    if (i < 128 * 128) {
        int k = i >> 7, n = i & 127;
        w1t[n * 128 + k] = f32_to_bf16(W1[k * 128 + n]);
    }
    if (i < 128 * 64) {
        int k = i >> 6, n = i & 63;
        w2t[n * 128 + k] = f32_to_bf16(W2[k * 64 + n]);
    }
}

// ---------------- GEMM1 (MFMA): h1b = bf16(x @ W1) ----------------
// 256 thr = 4 waves; block tile 64 rows x 128 cols; K = 128 (4 steps of 32)
__global__ __launch_bounds__(256) void gemm1_mfma_kernel(
    const float* __restrict__ x, const ushort16* __restrict__ w1t,
    ushort16* __restrict__ h1b) {
    __shared__ __align__(16) ushort16 xs[64 * XPAD];
    __shared__ __align__(16) ushort16 wt[128 * XPAD];
    const int tid = threadIdx.x;
    const int block_row = blockIdx.x * 64;

    // stage W1^T: 128 rows x 128 ushorts = 2048 uint4
    {
        const uint4* g = (const uint4*)w1t;
        #pragma unroll
        for (int j = 0; j < 8; ++j) {
            int idx = tid + 256 * j;
            int row = idx >> 4, c = idx & 15;
            uint4 v = g[idx];
            *(uint4*)&wt[row * XPAD + c * 8] = v;
        }
    }
    // stage x tile: 64 rows x 128 f32 -> bf16
    {
        #pragma unroll
        for (int j = 0; j < 8; ++j) {
            int idx = tid + 256 * j;            // 0..2047 float4s
            int row = idx >> 5, c4 = idx & 31;
            int gr = block_row + row; if (gr >= N_NODES) gr = N_NODES - 1;
            float4 v = *(const float4*)(x + (size_t)gr * IN_CH + c4 * 4);
            uint32 p0 = (uint32)f32_to_bf16(v.x) | ((uint32)f32_to_bf16(v.y) << 16);
            uint32 p1 = (uint32)f32_to_bf16(v.z) | ((uint32)f32_to_bf16(v.w) << 16);
            uint32* dp = (uint32*)&xs[row * XPAD + c4 * 4];
            dp[0] = p0; dp[1] = p1;
        }
    }
    __syncthreads();

    const int wv = tid >> 6, lane = tid & 63;
    const int r16 = lane & 15, kq = lane >> 4;
    f32x4 acc[8];
    #pragma unroll
    for (int n = 0; n < 8; ++n) acc[n] = (f32x4){0.f, 0.f, 0.f, 0.f};

    const ushort16* xrow = &xs[(wv * 16 + r16) * XPAD + kq * 8];
    #pragma unroll
    for (int kk = 0; kk < 4; ++kk) {
        short8 a = *(const short8*)(xrow + kk * 32);
        #pragma unroll
        for (int n = 0; n < 8; ++n) {
            short8 b = *(const short8*)&wt[(n * 16 + r16) * XPAD + kk * 32 + kq * 8];
            acc[n] = __builtin_amdgcn_mfma_f32_16x16x32_bf16(a, b, acc[n], 0, 0, 0);
        }
    }

    #pragma unroll
    for (int n = 0; n < 8; ++n) {
        #pragma unroll
        for (int j = 0; j < 4; ++j) {
            int gr = block_row + wv * 16 + kq * 4 + j;
            if (gr < N_NODES)
                h1b[(size_t)gr * HID + n * 16 + r16] = f32_to_bf16(acc[n][j]);
        }
    }
}

// ---------------- gather layer 1 (shfl-broadcast edges) ----------------
__global__ __launch_bounds__(256) void gather1_kernel(
    const int* __restrict__ offs, const int* __restrict__ degi,
    const ushort16* __restrict__ ebuf16, const float* __restrict__ dinv,
    const ushort16* __restrict__ h1b, float* __restrict__ agg1) {
    int node = blockIdx.x * 4 + (threadIdx.x >> 6);
    int lane = threadIdx.x & 63;
    if (node >= N_NODES) return;
    float di = dinv[node];
    int beg = offs[node];
    int cnt = degi[node];

    uint32 us = ((const uint32*)(h1b + (size_t)node * HID))[lane];
    float ax = bf16lo_to_f32(us) * di * di;
    float ay = bf16hi_to_f32(us) * di * di;

    for (int base = 0; base < cnt; base += 64) {
        int m = min(cnt - base, 64);
        int e_l = 0; float w_l = 0.f;
        if (lane < m) { e_l = ebuf16[beg + base + lane]; w_l = dinv[e_l] * di; }
        int i = 0;
        for (; i + 4 <= m; i += 4) {
            int s0 = __shfl(e_l, i),     s1 = __shfl(e_l, i + 1);
            int s2 = __shfl(e_l, i + 2), s3 = __shfl(e_l, i + 3);
            float w0 = __shfl(w_l, i),     w1 = __shfl(w_l, i + 1);
            float w2 = __shfl(w_l, i + 2), w3 = __shfl(w_l, i + 3);
            uint32 u0 = ((const uint32*)(h1b + (size_t)s0 * HID))[lane];
            uint32 u1 = ((const uint32*)(h1b + (size_t)s1 * HID))[lane];
            uint32 u2 = ((const uint32*)(h1b + (size_t)s2 * HID))[lane];
            uint32 u3 = ((const uint32*)(h1b + (size_t)s3 * HID))[lane];
            ax += bf16lo_to_f32(u0) * w0 + bf16lo_to_f32(u1) * w1
                + bf16lo_to_f32(u2) * w2 + bf16lo_to_f32(u3) * w3;
            ay += bf16hi_to_f32(u0) * w0 + bf16hi_to_f32(u1) * w1
                + bf16hi_to_f32(u2) * w2 + bf16hi_to_f32(u3) * w3;
        }
        for (; i < m; ++i) {
            int s0 = __shfl(e_l, i);
            float w0 = __shfl(w_l, i);
            uint32 u0 = ((const uint32*)(h1b + (size_t)s0 * HID))[lane];
            ax += bf16lo_to_f32(u0) * w0;
            ay += bf16hi_to_f32(u0) * w0;
        }
    }
    float2 r; r.x = ax; r.y = ay;
    ((float2*)(agg1 + (size_t)node * HID))[lane] = r;
}

// ---------------- GEMM2 (MFMA): h2b = bf16(tanh(agg1+b1) @ W2) ----------------
__global__ __launch_bounds__(256) void gemm2_mfma_kernel(
    const float* __restrict__ agg1, const float* __restrict__ b1,
    const ushort16* __restrict__ w2t, ushort16* __restrict__ h2b) {
    __shared__ __align__(16) ushort16 xs[64 * XPAD];
    __shared__ __align__(16) ushort16 wt[64 * XPAD];
    const int tid = threadIdx.x;
    const int block_row = blockIdx.x * 64;

    // stage W2^T: 64 rows x 128 ushorts = 1024 uint4
    {
        const uint4* g = (const uint4*)w2t;
        #pragma unroll
        for (int j = 0; j < 4; ++j) {
            int idx = tid + 256 * j;
            int row = idx >> 4, c = idx & 15;
            uint4 v = g[idx];
            *(uint4*)&wt[row * XPAD + c * 8] = v;
        }
    }
    // stage tanh(agg1 + b1) tile as bf16
    {
        #pragma unroll
        for (int j = 0; j < 8; ++j) {
            int idx = tid + 256 * j;
            int row = idx >> 5, c4 = idx & 31;
            int gr = block_row + row; if (gr >= N_NODES) gr = N_NODES - 1;
            float4 v = *(const float4*)(agg1 + (size_t)gr * HID + c4 * 4);
            float4 bb = *(const float4*)(b1 + c4 * 4);
            float t0 = tanhf(v.x + bb.x), t1 = tanhf(v.y + bb.y);
            float t2 = tanhf(v.z + bb.z), t3 = tanhf(v.w + bb.w);
            uint32 p0 = (uint32)f32_to_bf16(t0) | ((uint32)f32_to_bf16(t1) << 16);
            uint32 p1 = (uint32)f32_to_bf16(t2) | ((uint32)f32_to_bf16(t3) << 16);
            uint32* dp = (uint32*)&xs[row * XPAD + c4 * 4];
            dp[0] = p0; dp[1] = p1;
        }
    }
    __syncthreads();

    const int wv = tid >> 6, lane = tid & 63;
    const int r16 = lane & 15, kq = lane >> 4;
    f32x4 acc[4];
    #pragma unroll
    for (int n = 0; n < 4; ++n) acc[n] = (f32x4){0.f, 0.f, 0.f, 0.f};

    const ushort16* xrow = &xs[(wv * 16 + r16) * XPAD + kq * 8];
    #pragma unroll
    for (int kk = 0; kk < 4; ++kk) {
        short8 a = *(const short8*)(xrow + kk * 32);
        #pragma unroll
        for (int n = 0; n < 4; ++n) {
            short8 b = *(const short8*)&wt[(n * 16 + r16) * XPAD + kk * 32 + kq * 8];
            acc[n] = __builtin_amdgcn_mfma_f32_16x16x32_bf16(a, b, acc[n], 0, 0, 0);
        }
    }

    #pragma unroll
    for (int n = 0; n < 4; ++n) {
        #pragma unroll
        for (int j = 0; j < 4; ++j) {
            int gr = block_row + wv * 16 + kq * 4 + j;
            if (gr < N_NODES)
                h2b[(size_t)gr * OUT_CH + n * 16 + r16] = f32_to_bf16(acc[n][j]);
        }
    }
}

// ---------------- gather layer 2 (shfl-broadcast edges) ----------------
__global__ __launch_bounds__(256) void gather2_kernel(
    const int* __restrict__ offs, const int* __restrict__ degi,
    const ushort16* __restrict__ ebuf16, const float* __restrict__ dinv,
    const ushort16* __restrict__ h2b, const float* __restrict__ b2,
    float* __restrict__ out) {
    int node = blockIdx.x * 4 + (threadIdx.x >> 6);
    int lane = threadIdx.x & 63;
    if (node >= N_NODES) return;
    float di = dinv[node];
    int beg = offs[node];
    int cnt = degi[node];

    float self = __uint_as_float(((uint32)h2b[(size_t)node * OUT_CH + lane]) << 16);
    float acc = b2[lane] + self * di * di;

    for (int base = 0; base < cnt; base += 64) {
        int m = min(cnt - base, 64);
        int e_l = 0; float w_l = 0.f;
        if (lane < m) { e_l = ebuf16[beg + base + lane]; w_l = dinv[e_l] * di; }
        int i = 0;
        for (; i + 4 <= m; i += 4) {
            int s0 = __shfl(e_l, i),     s1 = __shfl(e_l, i + 1);
            int s2 = __shfl(e_l, i + 2), s3 = __shfl(e_l, i + 3);
            float w0 = __shfl(w_l, i),     w1 = __shfl(w_l, i + 1);
            float w2 = __shfl(w_l, i + 2), w3 = __shfl(w_l, i + 3);
            float v0 = __uint_as_float(((uint32)h2b[(size_t)s0 * OUT_CH + lane]) << 16);
            float v1 = __uint_as_float(((uint32)h2b[(size_t)s1 * OUT_CH + lane]) << 16);
            float v2 = __uint_as_float(((uint32)h2b[(size_t)s2 * OUT_CH + lane]) << 16);
            float v3 = __uint_as_float(((uint32)h2b[(size_t)s3 * OUT_CH + lane]) << 16);
            acc += v0 * w0 + v1 * w1 + v2 * w2 + v3 * w3;
        }
        for (; i < m; ++i) {
            int s0 = __shfl(e_l, i);
            float w0 = __shfl(w_l, i);
            float v0 = __uint_as_float(((uint32)h2b[(size_t)s0 * OUT_CH + lane]) << 16);
            acc += v0 * w0;
        }
    }
    out[(size_t)node * OUT_CH + lane] = acc;
}

extern "C" void kernel_launch(void* const* d_in, const int* in_sizes, int n_in,
                              void* d_out, int out_size, void* d_ws, size_t ws_size,
                              hipStream_t stream) {
    const float* x  = (const float*)d_in[0];
    const int*   ei = (const int*)d_in[1];
    const float* W1 = (const float*)d_in[2];
    const float* b1 = (const float*)d_in[3];
    const float* W2 = (const float*)d_in[4];
    const float* b2 = (const float*)d_in[5];
    float* out = (float*)d_out;

    const int E = in_sizes[1] / 2;   // edge_index is [2, E]
    const int* src = ei;
    const int* dst = ei + E;

    // workspace layout
    float* dinv   = (float*)d_ws;                 // N
    int* degi     = (int*)(dinv + N_NODES);       // N
    int* offs     = degi + N_NODES;               // N
    int* gcur     = offs + N_NODES;               // NCB
    int* ecnt     = gcur + NCB;                   // NCB
    int* eoff     = ecnt + NCB;                   // NCB
    ushort16* w1t = (ushort16*)(eoff + NCB);      // 128*128
    ushort16* w2t = w1t + 128 * 128;              // 64*128
    ushort16* ebuf16 = w2t + 64 * 128;            // E (u16)
    uintptr_t p   = (uintptr_t)(ebuf16 + E);
    p = (p + 15) & ~(uintptr_t)15;
    float* agg1   = (float*)p;                        // N*128 f32
    uint32* ebuf2 = (uint32*)agg1;                    // NCB*CAP u32, aliases agg1 (used before it)
    ushort16* h1b = (ushort16*)(agg1 + (size_t)N_NODES * HID);  // N*128 bf16
    ushort16* h2b = h1b + (size_t)N_NODES * HID;                // N*64 bf16

    curinit_kernel<<<1, 256, 0, stream>>>(gcur);
    passA_kernel<<<(E + APB - 1) / APB, 256, 0, stream>>>(src, dst, gcur, ebuf2, E);
    interlude_kernel<<<1, 256, 0, stream>>>(gcur, ecnt, eoff);
    passB_kernel<<<NCB, 256, 0, stream>>>(ebuf2, ecnt, eoff, ebuf16, offs, degi, dinv);
    prep_w_kernel<<<64, 256, 0, stream>>>(W1, W2, w1t, w2t);

    gemm1_mfma_kernel<<<(N_NODES + 63) / 64, 256, 0, stream>>>(x, w1t, h1b);
    gather1_kernel<<<(N_NODES + 3) / 4, 256, 0, stream>>>(offs, degi, ebuf16, dinv, h1b, agg1);
    gemm2_mfma_kernel<<<(N_NODES + 63) / 64, 256, 0, stream>>>(agg1, b1, w2t, h2b);
    gather2_kernel<<<(N_NODES + 3) / 4, 256, 0, stream>>>(offs, degi, ebuf16, dinv, h2b, b2, out);
}

// Round 7
// 121.120 us; speedup vs baseline: 7.8536x; 1.0664x over previous
//
#include <hip/hip_runtime.h>
#include <stdint.h>

#define N_NODES 50000
#define IN_CH   128
#define HID     128
#define OUT_CH  64

#define CBITS 8
#define NCB   ((N_NODES + 255) >> 8)     // 196 coarse buckets (dst>>8)
#define CAP   8192                        // per-bucket capacity in ebuf2
#define APB   4096                        // edges per pass-A block

#define XPAD  136                         // ushorts per LDS row (128 + 8 pad)

typedef unsigned int   uint32;
typedef unsigned short ushort16;
typedef __attribute__((ext_vector_type(8))) short short8;   // 8 bf16
typedef __attribute__((ext_vector_type(4))) float f32x4;

static __device__ __forceinline__ ushort16 f32_to_bf16(float f) {
    uint32 u = __float_as_uint(f);
    u = (u + 0x7fffu + ((u >> 16) & 1u)) >> 16;   // RNE
    return (ushort16)u;
}
static __device__ __forceinline__ float bf16lo_to_f32(uint32 u) {
    return __uint_as_float(u << 16);
}
static __device__ __forceinline__ float bf16hi_to_f32(uint32 u) {
    return __uint_as_float(u & 0xffff0000u);
}

// ---------------- CSR build: two-level LDS radix sort by dst ----------------

// Pass A: coarse partition edges by dst>>8 into ebuf2 (entries: src | dst<<16)
// gcur[b] is a pure counter (memset to 0 before); slot = b*CAP + count.
__global__ __launch_bounds__(256) void passA_kernel(
    const int* __restrict__ src, const int* __restrict__ dst,
    int* __restrict__ gcur, uint32* __restrict__ ebuf2, int E) {
    __shared__ int hist[256];
    __shared__ int excl[256];
    __shared__ int fcur[256];
    __shared__ int gbase[256];
    __shared__ uint32 obuf[APB];
    const int t = threadIdx.x;
    const int e0 = blockIdx.x * APB;
    const int nv = min(APB, E - e0);

    hist[t] = 0;
    __syncthreads();

    uint32 u[16];
    #pragma unroll
    for (int j = 0; j < 16; ++j) {
        int i = t + 256 * j;
        u[j] = 0xffffffffu;
        if (i < nv) {
            int e = e0 + i;
            int s = src[e], d = dst[e];
            if ((unsigned)d < N_NODES && (unsigned)s < N_NODES) {
                u[j] = (uint32)s | ((uint32)d << 16);
                atomicAdd(&hist[(unsigned)d >> CBITS], 1);
            }
        }
    }
    __syncthreads();

    excl[t] = hist[t];
    __syncthreads();
    #pragma unroll
    for (int off = 1; off < 256; off <<= 1) {
        int v = (t >= off) ? excl[t - off] : 0;
        __syncthreads();
        excl[t] += v;
        __syncthreads();
    }
    int myexcl = excl[t] - hist[t];
    if (hist[t] > 0) gbase[t] = t * CAP + atomicAdd(&gcur[t], hist[t]);
    __syncthreads();
    excl[t] = myexcl;
    fcur[t] = myexcl;
    __syncthreads();

    #pragma unroll
    for (int j = 0; j < 16; ++j) {
        if (u[j] != 0xffffffffu) {
            int b = u[j] >> (16 + CBITS);
            int pos = atomicAdd(&fcur[b], 1);
            obuf[pos] = u[j];
        }
    }
    __syncthreads();

    for (int i = t; i < nv; i += 256) {
        uint32 v = obuf[i];
        int b = v >> (16 + CBITS);
        int gpos = gbase[b] + (i - excl[b]);
        if (gpos < (b + 1) * CAP) ebuf2[gpos] = v;   // capacity guard
    }
}

// Interlude: per-bucket counts + exclusive scan -> global edge offsets
__global__ __launch_bounds__(256) void interlude_kernel(
    const int* __restrict__ gcur, int* __restrict__ ecnt, int* __restrict__ eoff) {
    __shared__ int sd[256];
    int t = threadIdx.x;
    int c = (t < NCB) ? gcur[t] : 0;
    sd[t] = c;
    __syncthreads();
    #pragma unroll
    for (int off = 1; off < 256; off <<= 1) {
        int v = (t >= off) ? sd[t - off] : 0;
        __syncthreads();
        sd[t] += v;
        __syncthreads();
    }
    if (t < NCB) { ecnt[t] = c; eoff[t] = sd[t] - c; }
}

// Pass B: fine sort within bucket; emit u16 src list + degi/offs/dinv
__global__ __launch_bounds__(256) void passB_kernel(
    const uint32* __restrict__ ebuf2, const int* __restrict__ ecnt,
    const int* __restrict__ eoff, ushort16* __restrict__ ebuf16,
    int* __restrict__ offs, int* __restrict__ degi, float* __restrict__ dinv) {
    __shared__ uint32 sbuf[CAP];
    __shared__ ushort16 obuf[CAP];
    __shared__ int fh[256];
    __shared__ int fx[256];
    __shared__ int fc[256];
    const int b = blockIdx.x, t = threadIdx.x;
    const int nb = ecnt[b];
    const int base = b * CAP;
    const int obase = eoff[b];

    fh[t] = 0;
    __syncthreads();
    for (int i = t; i < nb; i += 256) {
        uint32 v = ebuf2[base + i];
        sbuf[i] = v;
        atomicAdd(&fh[(v >> 16) & 255], 1);
    }
    __syncthreads();

    fx[t] = fh[t];
    __syncthreads();
    #pragma unroll
    for (int off = 1; off < 256; off <<= 1) {
        int v = (t >= off) ? fx[t - off] : 0;
        __syncthreads();
        fx[t] += v;
        __syncthreads();
    }
    int ex = fx[t] - fh[t];
    fc[t] = ex;

    int n = b * 256 + t;
    if (n < N_NODES) {
        degi[n] = fh[t];
        offs[n] = obase + ex;
        dinv[n] = rsqrtf(1.0f + (float)fh[t]);
    }
    __syncthreads();

    for (int i = t; i < nb; i += 256) {
        uint32 v = sbuf[i];
        int nl = (v >> 16) & 255;
        int pos = atomicAdd(&fc[nl], 1);
        obuf[pos] = (ushort16)(v & 0xffffu);
    }
    __syncthreads();
    for (int i = t; i < nb; i += 256) ebuf16[obase + i] = obuf[i];
}

// ---------------- prep: W1^T, W2^T as bf16 [N][K] ----------------
__global__ __launch_bounds__(256) void prep_w_kernel(
    const float* __restrict__ W1, const float* __restrict__ W2,
    ushort16* __restrict__ w1t, ushort16* __restrict__ w2t) {
    int i = blockIdx.x * 256 + threadIdx.x;
    if (i < 128 * 128) {
        int k = i >> 7, n = i & 127;
        w1t[n * 128 + k] = f32_to_bf16(W1[k * 128 + n]);
    }
    if (i < 128 * 64) {
        int k = i >> 6, n = i & 63;
        w2t[n * 128 + k] = f32_to_bf16(W2[k * 64 + n]);
    }
}

// ---------------- GEMM1 (MFMA): h1b = bf16(x @ W1) ----------------
__global__ __launch_bounds__(256) void gemm1_mfma_kernel(
    const float* __restrict__ x, const ushort16* __restrict__ w1t,
    ushort16* __restrict__ h1b) {
    __shared__ __align__(16) ushort16 xs[64 * XPAD];
    __shared__ __align__(16) ushort16 wt[128 * XPAD];
    const int tid = threadIdx.x;
    const int block_row = blockIdx.x * 64;

    {
        const uint4* g = (const uint4*)w1t;
        #pragma unroll
        for (int j = 0; j < 8; ++j) {
            int idx = tid + 256 * j;
            int row = idx >> 4, c = idx & 15;
            uint4 v = g[idx];
            *(uint4*)&wt[row * XPAD + c * 8] = v;
        }
    }
    {
        #pragma unroll
        for (int j = 0; j < 8; ++j) {
            int idx = tid + 256 * j;            // 0..2047 float4s
            int row = idx >> 5, c4 = idx & 31;
            int gr = block_row + row; if (gr >= N_NODES) gr = N_NODES - 1;
            float4 v = *(const float4*)(x + (size_t)gr * IN_CH + c4 * 4);
            uint32 p0 = (uint32)f32_to_bf16(v.x) | ((uint32)f32_to_bf16(v.y) << 16);
            uint32 p1 = (uint32)f32_to_bf16(v.z) | ((uint32)f32_to_bf16(v.w) << 16);
            uint32* dp = (uint32*)&xs[row * XPAD + c4 * 4];
            dp[0] = p0; dp[1] = p1;
        }
    }
    __syncthreads();

    const int wv = tid >> 6, lane = tid & 63;
    const int r16 = lane & 15, kq = lane >> 4;
    f32x4 acc[8];
    #pragma unroll
    for (int n = 0; n < 8; ++n) acc[n] = (f32x4){0.f, 0.f, 0.f, 0.f};

    const ushort16* xrow = &xs[(wv * 16 + r16) * XPAD + kq * 8];
    #pragma unroll
    for (int kk = 0; kk < 4; ++kk) {
        short8 a = *(const short8*)(xrow + kk * 32);
        #pragma unroll
        for (int n = 0; n < 8; ++n) {
            short8 b = *(const short8*)&wt[(n * 16 + r16) * XPAD + kk * 32 + kq * 8];
            acc[n] = __builtin_amdgcn_mfma_f32_16x16x32_bf16(a, b, acc[n], 0, 0, 0);
        }
    }

    #pragma unroll
    for (int n = 0; n < 8; ++n) {
        #pragma unroll
        for (int j = 0; j < 4; ++j) {
            int gr = block_row + wv * 16 + kq * 4 + j;
            if (gr < N_NODES)
                h1b[(size_t)gr * HID + n * 16 + r16] = f32_to_bf16(acc[n][j]);
        }
    }
}

// ---------------- gather1 (fused act): a1b = bf16(tanh(Ahat*h1 + b1)) ----------------
__global__ __launch_bounds__(256) void gather1_kernel(
    const int* __restrict__ offs, const int* __restrict__ degi,
    const ushort16* __restrict__ ebuf16, const float* __restrict__ dinv,
    const ushort16* __restrict__ h1b, const float* __restrict__ b1,
    ushort16* __restrict__ a1b) {
    int node = blockIdx.x * 4 + (threadIdx.x >> 6);
    int lane = threadIdx.x & 63;
    if (node >= N_NODES) return;
    float di = dinv[node];
    int beg = offs[node];
    int cnt = degi[node];

    uint32 us = ((const uint32*)(h1b + (size_t)node * HID))[lane];
    float ax = bf16lo_to_f32(us) * di * di;
    float ay = bf16hi_to_f32(us) * di * di;

    for (int base = 0; base < cnt; base += 64) {
        int m = min(cnt - base, 64);
        int e_l = 0; float w_l = 0.f;
        if (lane < m) { e_l = ebuf16[beg + base + lane]; w_l = dinv[e_l] * di; }
        int i = 0;
        for (; i + 8 <= m; i += 8) {
            int s0 = __shfl(e_l, i),     s1 = __shfl(e_l, i + 1);
            int s2 = __shfl(e_l, i + 2), s3 = __shfl(e_l, i + 3);
            int s4 = __shfl(e_l, i + 4), s5 = __shfl(e_l, i + 5);
            int s6 = __shfl(e_l, i + 6), s7 = __shfl(e_l, i + 7);
            float w0 = __shfl(w_l, i),     w1 = __shfl(w_l, i + 1);
            float w2 = __shfl(w_l, i + 2), w3 = __shfl(w_l, i + 3);
            float w4 = __shfl(w_l, i + 4), w5 = __shfl(w_l, i + 5);
            float w6 = __shfl(w_l, i + 6), w7 = __shfl(w_l, i + 7);
            uint32 u0 = ((const uint32*)(h1b + (size_t)s0 * HID))[lane];
            uint32 u1 = ((const uint32*)(h1b + (size_t)s1 * HID))[lane];
            uint32 u2 = ((const uint32*)(h1b + (size_t)s2 * HID))[lane];
            uint32 u3 = ((const uint32*)(h1b + (size_t)s3 * HID))[lane];
            uint32 u4 = ((const uint32*)(h1b + (size_t)s4 * HID))[lane];
            uint32 u5 = ((const uint32*)(h1b + (size_t)s5 * HID))[lane];
            uint32 u6 = ((const uint32*)(h1b + (size_t)s6 * HID))[lane];
            uint32 u7 = ((const uint32*)(h1b + (size_t)s7 * HID))[lane];
            ax += bf16lo_to_f32(u0) * w0 + bf16lo_to_f32(u1) * w1
                + bf16lo_to_f32(u2) * w2 + bf16lo_to_f32(u3) * w3
                + bf16lo_to_f32(u4) * w4 + bf16lo_to_f32(u5) * w5
                + bf16lo_to_f32(u6) * w6 + bf16lo_to_f32(u7) * w7;
            ay += bf16hi_to_f32(u0) * w0 + bf16hi_to_f32(u1) * w1
                + bf16hi_to_f32(u2) * w2 + bf16hi_to_f32(u3) * w3
                + bf16hi_to_f32(u4) * w4 + bf16hi_to_f32(u5) * w5
                + bf16hi_to_f32(u6) * w6 + bf16hi_to_f32(u7) * w7;
        }
        for (; i + 2 <= m; i += 2) {
            int s0 = __shfl(e_l, i), s1 = __shfl(e_l, i + 1);
            float w0 = __shfl(w_l, i), w1 = __shfl(w_l, i + 1);
            uint32 u0 = ((const uint32*)(h1b + (size_t)s0 * HID))[lane];
            uint32 u1 = ((const uint32*)(h1b + (size_t)s1 * HID))[lane];
            ax += bf16lo_to_f32(u0) * w0 + bf16lo_to_f32(u1) * w1;
            ay += bf16hi_to_f32(u0) * w0 + bf16hi_to_f32(u1) * w1;
        }
        for (; i < m; ++i) {
            int s0 = __shfl(e_l, i);
            float w0 = __shfl(w_l, i);
            uint32 u0 = ((const uint32*)(h1b + (size_t)s0 * HID))[lane];
            ax += bf16lo_to_f32(u0) * w0;
            ay += bf16hi_to_f32(u0) * w0;
        }
    }
    float2 bb = ((const float2*)b1)[lane];
    float tx = tanhf(ax + bb.x);
    float ty = tanhf(ay + bb.y);
    uint32 pk = (uint32)f32_to_bf16(tx) | ((uint32)f32_to_bf16(ty) << 16);
    ((uint32*)(a1b + (size_t)node * HID))[lane] = pk;
}

// ---------------- GEMM2 (MFMA): h2b = bf16(a1b @ W2) ----------------
__global__ __launch_bounds__(256) void gemm2_mfma_kernel(
    const ushort16* __restrict__ a1b, const ushort16* __restrict__ w2t,
    ushort16* __restrict__ h2b) {
    __shared__ __align__(16) ushort16 xs[64 * XPAD];
    __shared__ __align__(16) ushort16 wt[64 * XPAD];
    const int tid = threadIdx.x;
    const int block_row = blockIdx.x * 64;

    {
        const uint4* g = (const uint4*)w2t;
        #pragma unroll
        for (int j = 0; j < 4; ++j) {
            int idx = tid + 256 * j;
            int row = idx >> 4, c = idx & 15;
            uint4 v = g[idx];
            *(uint4*)&wt[row * XPAD + c * 8] = v;
        }
    }
    {
        #pragma unroll
        for (int j = 0; j < 4; ++j) {
            int idx = tid + 256 * j;            // 0..1023 uint4s
            int row = idx >> 4, c = idx & 15;
            int gr = block_row + row; if (gr >= N_NODES) gr = N_NODES - 1;
            uint4 v = *(const uint4*)(a1b + (size_t)gr * HID + c * 8);
            *(uint4*)&xs[row * XPAD + c * 8] = v;
        }
    }
    __syncthreads();

    const int wv = tid >> 6, lane = tid & 63;
    const int r16 = lane & 15, kq = lane >> 4;
    f32x4 acc[4];
    #pragma unroll
    for (int n = 0; n < 4; ++n) acc[n] = (f32x4){0.f, 0.f, 0.f, 0.f};

    const ushort16* xrow = &xs[(wv * 16 + r16) * XPAD + kq * 8];
    #pragma unroll
    for (int kk = 0; kk < 4; ++kk) {
        short8 a = *(const short8*)(xrow + kk * 32);
        #pragma unroll
        for (int n = 0; n < 4; ++n) {
            short8 b = *(const short8*)&wt[(n * 16 + r16) * XPAD + kk * 32 + kq * 8];
            acc[n] = __builtin_amdgcn_mfma_f32_16x16x32_bf16(a, b, acc[n], 0, 0, 0);
        }
    }

    #pragma unroll
    for (int n = 0; n < 4; ++n) {
        #pragma unroll
        for (int j = 0; j < 4; ++j) {
            int gr = block_row + wv * 16 + kq * 4 + j;
            if (gr < N_NODES)
                h2b[(size_t)gr * OUT_CH + n * 16 + r16] = f32_to_bf16(acc[n][j]);
        }
    }
}

// ---------------- gather2: out = b2 + Ahat*h2 ----------------
__global__ __launch_bounds__(256) void gather2_kernel(
    const int* __restrict__ offs, const int* __restrict__ degi,
    const ushort16* __restrict__ ebuf16, const float* __restrict__ dinv,
    const ushort16* __restrict__ h2b, const float* __restrict__ b2,
    float* __restrict__ out) {
    int node = blockIdx.x * 4 + (threadIdx.x >> 6);
    int lane = threadIdx.x & 63;
    if (node >= N_NODES) return;
    float di = dinv[node];
    int beg = offs[node];
    int cnt = degi[node];

    float self = __uint_as_float(((uint32)h2b[(size_t)node * OUT_CH + lane]) << 16);
    float acc = b2[lane] + self * di * di;

    for (int base = 0; base < cnt; base += 64) {
        int m = min(cnt - base, 64);
        int e_l = 0; float w_l = 0.f;
        if (lane < m) { e_l = ebuf16[beg + base + lane]; w_l = dinv[e_l] * di; }
        int i = 0;
        for (; i + 8 <= m; i += 8) {
            int s0 = __shfl(e_l, i),     s1 = __shfl(e_l, i + 1);
            int s2 = __shfl(e_l, i + 2), s3 = __shfl(e_l, i + 3);
            int s4 = __shfl(e_l, i + 4), s5 = __shfl(e_l, i + 5);
            int s6 = __shfl(e_l, i + 6), s7 = __shfl(e_l, i + 7);
            float w0 = __shfl(w_l, i),     w1 = __shfl(w_l, i + 1);
            float w2 = __shfl(w_l, i + 2), w3 = __shfl(w_l, i + 3);
            float w4 = __shfl(w_l, i + 4), w5 = __shfl(w_l, i + 5);
            float w6 = __shfl(w_l, i + 6), w7 = __shfl(w_l, i + 7);
            float v0 = __uint_as_float(((uint32)h2b[(size_t)s0 * OUT_CH + lane]) << 16);
            float v1 = __uint_as_float(((uint32)h2b[(size_t)s1 * OUT_CH + lane]) << 16);
            float v2 = __uint_as_float(((uint32)h2b[(size_t)s2 * OUT_CH + lane]) << 16);
            float v3 = __uint_as_float(((uint32)h2b[(size_t)s3 * OUT_CH + lane]) << 16);
            float v4 = __uint_as_float(((uint32)h2b[(size_t)s4 * OUT_CH + lane]) << 16);
            float v5 = __uint_as_float(((uint32)h2b[(size_t)s5 * OUT_CH + lane]) << 16);
            float v6 = __uint_as_float(((uint32)h2b[(size_t)s6 * OUT_CH + lane]) << 16);
            float v7 = __uint_as_float(((uint32)h2b[(size_t)s7 * OUT_CH + lane]) << 16);
            acc += v0 * w0 + v1 * w1 + v2 * w2 + v3 * w3
                 + v4 * w4 + v5 * w5 + v6 * w6 + v7 * w7;
        }
        for (; i + 2 <= m; i += 2) {
            int s0 = __shfl(e_l, i), s1 = __shfl(e_l, i + 1);
            float w0 = __shfl(w_l, i), w1 = __shfl(w_l, i + 1);
            float v0 = __uint_as_float(((uint32)h2b[(size_t)s0 * OUT_CH + lane]) << 16);
            float v1 = __uint_as_float(((uint32)h2b[(size_t)s1 * OUT_CH + lane]) << 16);
            acc += v0 * w0 + v1 * w1;
        }
        for (; i < m; ++i) {
            int s0 = __shfl(e_l, i);
            float w0 = __shfl(w_l, i);
            float v0 = __uint_as_float(((uint32)h2b[(size_t)s0 * OUT_CH + lane]) << 16);
            acc += v0 * w0;
        }
    }
    out[(size_t)node * OUT_CH + lane] = acc;
}

extern "C" void kernel_launch(void* const* d_in, const int* in_sizes, int n_in,
                              void* d_out, int out_size, void* d_ws, size_t ws_size,
                              hipStream_t stream) {
    const float* x  = (const float*)d_in[0];
    const int*   ei = (const int*)d_in[1];
    const float* W1 = (const float*)d_in[2];
    const float* b1 = (const float*)d_in[3];
    const float* W2 = (const float*)d_in[4];
    const float* b2 = (const float*)d_in[5];
    float* out = (float*)d_out;

    const int E = in_sizes[1] / 2;   // edge_index is [2, E]
    const int* src = ei;
    const int* dst = ei + E;

    // workspace layout
    float* dinv   = (float*)d_ws;                 // N
    int* degi     = (int*)(dinv + N_NODES);       // N
    int* offs     = degi + N_NODES;               // N
    int* gcur     = offs + N_NODES;               // NCB
    int* ecnt     = gcur + NCB;                   // NCB
    int* eoff     = ecnt + NCB;                   // NCB
    ushort16* w1t = (ushort16*)(eoff + NCB);      // 128*128
    ushort16* w2t = w1t + 128 * 128;              // 64*128
    ushort16* ebuf16 = w2t + 64 * 128;            // E (u16)
    uintptr_t p   = (uintptr_t)(ebuf16 + E);
    p = (p + 15) & ~(uintptr_t)15;
    ushort16* a1b = (ushort16*)p;                     // N*128 bf16
    uint32* ebuf2 = (uint32*)a1b;                     // NCB*CAP u32, aliases a1b (used before it)
    ushort16* h1b = a1b + (size_t)N_NODES * HID;      // N*128 bf16
    ushort16* h2b = h1b + (size_t)N_NODES * HID;      // N*64 bf16

    hipMemsetAsync(gcur, 0, NCB * sizeof(int), stream);
    passA_kernel<<<(E + APB - 1) / APB, 256, 0, stream>>>(src, dst, gcur, ebuf2, E);
    interlude_kernel<<<1, 256, 0, stream>>>(gcur, ecnt, eoff);
    passB_kernel<<<NCB, 256, 0, stream>>>(ebuf2, ecnt, eoff, ebuf16, offs, degi, dinv);
    prep_w_kernel<<<64, 256, 0, stream>>>(W1, W2, w1t, w2t);

    gemm1_mfma_kernel<<<(N_NODES + 63) / 64, 256, 0, stream>>>(x, w1t, h1b);
    gather1_kernel<<<(N_NODES + 3) / 4, 256, 0, stream>>>(offs, degi, ebuf16, dinv, h1b, b1, a1b);
    gemm2_mfma_kernel<<<(N_NODES + 63) / 64, 256, 0, stream>>>(a1b, w2t, h2b);
    gather2_kernel<<<(N_NODES + 3) / 4, 256, 0, stream>>>(offs, degi, ebuf16, dinv, h2b, b2, out);
}

// Round 8
// 113.319 us; speedup vs baseline: 8.3942x; 1.0688x over previous
//
#include <hip/hip_runtime.h>
#include <stdint.h>

#define N_NODES 50000
#define IN_CH   128
#define HID     128
#define OUT_CH  64

#define CBITS 8
#define NCB   196                         // coarse buckets (dst>>8)
#define CAP   8192                        // per-bucket capacity in ebuf2/ebuf16
#define APB   4096                        // edges per pass-A block

#define XPAD  136                         // ushorts per LDS row (128 + 8 pad)
#define G1BLK 782                         // gemm tiles: ceil(50000/64)

typedef unsigned int   uint32;
typedef unsigned short ushort16;
typedef __attribute__((ext_vector_type(8))) short short8;   // 8 bf16
typedef __attribute__((ext_vector_type(4))) float f32x4;

static __device__ __forceinline__ ushort16 f32_to_bf16(float f) {
    uint32 u = __float_as_uint(f);
    u = (u + 0x7fffu + ((u >> 16) & 1u)) >> 16;   // RNE
    return (ushort16)u;
}
static __device__ __forceinline__ float bf16lo_to_f32(uint32 u) {
    return __uint_as_float(u << 16);
}
static __device__ __forceinline__ float bf16hi_to_f32(uint32 u) {
    return __uint_as_float(u & 0xffff0000u);
}
#define RLI(v, l) __builtin_amdgcn_readlane((v), (l))
#define RLF(v, l) __uint_as_float((uint32)__builtin_amdgcn_readlane((int)__float_as_uint(v), (l)))

// ---------------- build1: passA (blocks < nA) ∥ prep_w (blocks >= nA) ----------------
// passA: coarse partition edges by dst>>8 into ebuf2 (entries: src | dst<<16)
__global__ __launch_bounds__(256) void build1_kernel(
    const int* __restrict__ src, const int* __restrict__ dst,
    int* __restrict__ gcur, uint32* __restrict__ ebuf2, int E, int nA,
    const float* __restrict__ W1, const float* __restrict__ W2,
    ushort16* __restrict__ w1t, ushort16* __restrict__ w2t) {
    __shared__ int hist[256];
    __shared__ int excl[256];
    __shared__ int fcur[256];
    __shared__ int gbase[256];
    __shared__ uint32 obuf[APB];
    const int t = threadIdx.x;

    if ((int)blockIdx.x >= nA) {   // prep_w part: 64 blocks
        int i = ((int)blockIdx.x - nA) * 256 + t;
        if (i < 128 * 128) {
            int k = i >> 7, n = i & 127;
            w1t[n * 128 + k] = f32_to_bf16(W1[k * 128 + n]);
        }
        if (i < 128 * 64) {
            int k = i >> 6, n = i & 63;
            w2t[n * 128 + k] = f32_to_bf16(W2[k * 64 + n]);
        }
        return;
    }

    const int e0 = blockIdx.x * APB;
    const int nv = min(APB, E - e0);

    hist[t] = 0;
    __syncthreads();

    uint32 u[16];
    #pragma unroll
    for (int j = 0; j < 16; ++j) {
        int i = t + 256 * j;
        u[j] = 0xffffffffu;
        if (i < nv) {
            int e = e0 + i;
            int s = src[e], d = dst[e];
            if ((unsigned)d < N_NODES && (unsigned)s < N_NODES) {
                u[j] = (uint32)s | ((uint32)d << 16);
                atomicAdd(&hist[(unsigned)d >> CBITS], 1);
            }
        }
    }
    __syncthreads();

    excl[t] = hist[t];
    __syncthreads();
    #pragma unroll
    for (int off = 1; off < 256; off <<= 1) {
        int v = (t >= off) ? excl[t - off] : 0;
        __syncthreads();
        excl[t] += v;
        __syncthreads();
    }
    int myexcl = excl[t] - hist[t];
    if (hist[t] > 0) gbase[t] = t * CAP + atomicAdd(&gcur[t], hist[t]);
    __syncthreads();
    excl[t] = myexcl;
    fcur[t] = myexcl;
    __syncthreads();

    #pragma unroll
    for (int j = 0; j < 16; ++j) {
        if (u[j] != 0xffffffffu) {
            int b = u[j] >> (16 + CBITS);
            int pos = atomicAdd(&fcur[b], 1);
            obuf[pos] = u[j];
        }
    }
    __syncthreads();

    for (int i = t; i < nv; i += 256) {
        uint32 v = obuf[i];
        int b = v >> (16 + CBITS);
        int gpos = gbase[b] + (i - excl[b]);
        if (gpos < (b + 1) * CAP) ebuf2[gpos] = v;   // capacity guard
    }
}

// ---------------- build2: passB (blocks < NCB) ∥ gemm1 (blocks >= NCB) ----------------
__global__ __launch_bounds__(256) void build2_kernel(
    const uint32* __restrict__ ebuf2, const int* __restrict__ gcur,
    ushort16* __restrict__ ebuf16, int* __restrict__ offs,
    int* __restrict__ degi, float* __restrict__ dinv,
    const float* __restrict__ x, const ushort16* __restrict__ w1t,
    ushort16* __restrict__ h1b) {
    __shared__ __align__(16) char smem[53248];
    const int t = threadIdx.x;

    if (blockIdx.x >= NCB) {
        // ---- gemm1: h1b = bf16(x @ W1), tile 64 rows x 128 cols ----
        ushort16* xs = (ushort16*)smem;                       // 64*XPAD
        ushort16* wt = (ushort16*)(smem + 64 * XPAD * 2);     // 128*XPAD
        const int block_row = ((int)blockIdx.x - NCB) * 64;

        {
            const uint4* g = (const uint4*)w1t;
            #pragma unroll
            for (int j = 0; j < 8; ++j) {
                int idx = t + 256 * j;
                int row = idx >> 4, c = idx & 15;
                uint4 v = g[idx];
                *(uint4*)&wt[row * XPAD + c * 8] = v;
            }
        }
        {
            #pragma unroll
            for (int j = 0; j < 8; ++j) {
                int idx = t + 256 * j;            // 0..2047 float4s
                int row = idx >> 5, c4 = idx & 31;
                int gr = block_row + row; if (gr >= N_NODES) gr = N_NODES - 1;
                float4 v = *(const float4*)(x + (size_t)gr * IN_CH + c4 * 4);
                uint32 p0 = (uint32)f32_to_bf16(v.x) | ((uint32)f32_to_bf16(v.y) << 16);
                uint32 p1 = (uint32)f32_to_bf16(v.z) | ((uint32)f32_to_bf16(v.w) << 16);
                uint32* dp = (uint32*)&xs[row * XPAD + c4 * 4];
                dp[0] = p0; dp[1] = p1;
            }
        }
        __syncthreads();

        const int wv = t >> 6, lane = t & 63;
        const int r16 = lane & 15, kq = lane >> 4;
        f32x4 acc[8];
        #pragma unroll
        for (int n = 0; n < 8; ++n) acc[n] = (f32x4){0.f, 0.f, 0.f, 0.f};

        const ushort16* xrow = &xs[(wv * 16 + r16) * XPAD + kq * 8];
        #pragma unroll
        for (int kk = 0; kk < 4; ++kk) {
            short8 a = *(const short8*)(xrow + kk * 32);
            #pragma unroll
            for (int n = 0; n < 8; ++n) {
                short8 b = *(const short8*)&wt[(n * 16 + r16) * XPAD + kk * 32 + kq * 8];
                acc[n] = __builtin_amdgcn_mfma_f32_16x16x32_bf16(a, b, acc[n], 0, 0, 0);
            }
        }

        #pragma unroll
        for (int n = 0; n < 8; ++n) {
            #pragma unroll
            for (int j = 0; j < 4; ++j) {
                int gr = block_row + wv * 16 + kq * 4 + j;
                if (gr < N_NODES)
                    h1b[(size_t)gr * HID + n * 16 + r16] = f32_to_bf16(acc[n][j]);
            }
        }
        return;
    }

    // ---- passB: fine sort within bucket; emits u16 src list + degi/offs/dinv ----
    uint32*   sbuf = (uint32*)smem;                       // CAP u32
    ushort16* obuf = (ushort16*)(smem + CAP * 4);         // CAP u16
    int* fh = (int*)(smem + CAP * 4 + CAP * 2);
    int* fx = fh + 256;
    int* fc = fx + 256;
    int* gs = fc + 256;
    const int b = blockIdx.x;

    // per-block redundant scan of bucket counts -> this bucket's edge offset
    {
        int c = (t < NCB) ? min(gcur[t], CAP) : 0;
        gs[t] = c;
        __syncthreads();
        #pragma unroll
        for (int off = 1; off < 256; off <<= 1) {
            int v = (t >= off) ? gs[t - off] : 0;
            __syncthreads();
            gs[t] += v;
            __syncthreads();
        }
    }
    const int nb = min(gcur[b], CAP);
    const int obase = gs[b] - nb;
    __syncthreads();

    fh[t] = 0;
    __syncthreads();
    for (int i = t; i < nb; i += 256) {
        uint32 v = ebuf2[b * CAP + i];
        sbuf[i] = v;
        atomicAdd(&fh[(v >> 16) & 255], 1);
    }
    __syncthreads();

    fx[t] = fh[t];
    __syncthreads();
    #pragma unroll
    for (int off = 1; off < 256; off <<= 1) {
        int v = (t >= off) ? fx[t - off] : 0;
        __syncthreads();
        fx[t] += v;
        __syncthreads();
    }
    int ex = fx[t] - fh[t];
    fc[t] = ex;

    int n = b * 256 + t;
    if (n < N_NODES) {
        degi[n] = fh[t];
        offs[n] = obase + ex;
        dinv[n] = rsqrtf(1.0f + (float)fh[t]);
    }
    __syncthreads();

    for (int i = t; i < nb; i += 256) {
        uint32 v = sbuf[i];
        int nl = (v >> 16) & 255;
        int pos = atomicAdd(&fc[nl], 1);
        obuf[pos] = (ushort16)(v & 0xffffu);
    }
    __syncthreads();
    for (int i = t; i < nb; i += 256) ebuf16[obase + i] = obuf[i];
}

// ---------------- gather1 (fused act): a1b = bf16(tanh(Ahat*h1 + b1)) ----------------
__global__ __launch_bounds__(256) void gather1_kernel(
    const int* __restrict__ offs, const int* __restrict__ degi,
    const ushort16* __restrict__ ebuf16, const float* __restrict__ dinv,
    const ushort16* __restrict__ h1b, const float* __restrict__ b1,
    ushort16* __restrict__ a1b) {
    int node = blockIdx.x * 4 + (threadIdx.x >> 6);
    int lane = threadIdx.x & 63;
    if (node >= N_NODES) return;
    float di = dinv[node];
    int beg = offs[node];
    int cnt = degi[node];

    uint32 us = ((const uint32*)(h1b + (size_t)node * HID))[lane];
    float ax = bf16lo_to_f32(us) * di * di;
    float ay = bf16hi_to_f32(us) * di * di;

    for (int base = 0; base < cnt; base += 64) {
        int m = min(cnt - base, 64);
        int e_l = 0; float w_l = 0.f;
        if (lane < m) {
            e_l = (int)ebuf16[beg + base + lane];
            e_l = min(e_l, N_NODES - 1);          // harden vs poison under replay
            w_l = dinv[e_l] * di;
        }
        int i = 0;
        for (; i + 8 <= m; i += 8) {
            int s0 = RLI(e_l, i),     s1 = RLI(e_l, i + 1);
            int s2 = RLI(e_l, i + 2), s3 = RLI(e_l, i + 3);
            int s4 = RLI(e_l, i + 4), s5 = RLI(e_l, i + 5);
            int s6 = RLI(e_l, i + 6), s7 = RLI(e_l, i + 7);
            float w0 = RLF(w_l, i),     w1 = RLF(w_l, i + 1);
            float w2 = RLF(w_l, i + 2), w3 = RLF(w_l, i + 3);
            float w4 = RLF(w_l, i + 4), w5 = RLF(w_l, i + 5);
            float w6 = RLF(w_l, i + 6), w7 = RLF(w_l, i + 7);
            uint32 u0 = ((const uint32*)(h1b + (size_t)s0 * HID))[lane];
            uint32 u1 = ((const uint32*)(h1b + (size_t)s1 * HID))[lane];
            uint32 u2 = ((const uint32*)(h1b + (size_t)s2 * HID))[lane];
            uint32 u3 = ((const uint32*)(h1b + (size_t)s3 * HID))[lane];
            uint32 u4 = ((const uint32*)(h1b + (size_t)s4 * HID))[lane];
            uint32 u5 = ((const uint32*)(h1b + (size_t)s5 * HID))[lane];
            uint32 u6 = ((const uint32*)(h1b + (size_t)s6 * HID))[lane];
            uint32 u7 = ((const uint32*)(h1b + (size_t)s7 * HID))[lane];
            ax += bf16lo_to_f32(u0) * w0 + bf16lo_to_f32(u1) * w1
                + bf16lo_to_f32(u2) * w2 + bf16lo_to_f32(u3) * w3
                + bf16lo_to_f32(u4) * w4 + bf16lo_to_f32(u5) * w5
                + bf16lo_to_f32(u6) * w6 + bf16lo_to_f32(u7) * w7;
            ay += bf16hi_to_f32(u0) * w0 + bf16hi_to_f32(u1) * w1
                + bf16hi_to_f32(u2) * w2 + bf16hi_to_f32(u3) * w3
                + bf16hi_to_f32(u4) * w4 + bf16hi_to_f32(u5) * w5
                + bf16hi_to_f32(u6) * w6 + bf16hi_to_f32(u7) * w7;
        }
        for (; i < m; ++i) {
            int s0 = RLI(e_l, i);
            float w0 = RLF(w_l, i);
            uint32 u0 = ((const uint32*)(h1b + (size_t)s0 * HID))[lane];
            ax += bf16lo_to_f32(u0) * w0;
            ay += bf16hi_to_f32(u0) * w0;
        }
    }
    float2 bb = ((const float2*)b1)[lane];
    float tx = tanhf(ax + bb.x);
    float ty = tanhf(ay + bb.y);
    uint32 pk = (uint32)f32_to_bf16(tx) | ((uint32)f32_to_bf16(ty) << 16);
    ((uint32*)(a1b + (size_t)node * HID))[lane] = pk;
}

// ---------------- GEMM2 (MFMA): h2b = bf16(a1b @ W2) ----------------
__global__ __launch_bounds__(256) void gemm2_mfma_kernel(
    const ushort16* __restrict__ a1b, const ushort16* __restrict__ w2t,
    ushort16* __restrict__ h2b) {
    __shared__ __align__(16) ushort16 xs[64 * XPAD];
    __shared__ __align__(16) ushort16 wt[64 * XPAD];
    const int tid = threadIdx.x;
    const int block_row = blockIdx.x * 64;

    {
        const uint4* g = (const uint4*)w2t;
        #pragma unroll
        for (int j = 0; j < 4; ++j) {
            int idx = tid + 256 * j;
            int row = idx >> 4, c = idx & 15;
            uint4 v = g[idx];
            *(uint4*)&wt[row * XPAD + c * 8] = v;
        }
    }
    {
        #pragma unroll
        for (int j = 0; j < 4; ++j) {
            int idx = tid + 256 * j;            // 0..1023 uint4s
            int row = idx >> 4, c = idx & 15;
            int gr = block_row + row; if (gr >= N_NODES) gr = N_NODES - 1;
            uint4 v = *(const uint4*)(a1b + (size_t)gr * HID + c * 8);
            *(uint4*)&xs[row * XPAD + c * 8] = v;
        }
    }
    __syncthreads();

    const int wv = tid >> 6, lane = tid & 63;
    const int r16 = lane & 15, kq = lane >> 4;
    f32x4 acc[4];
    #pragma unroll
    for (int n = 0; n < 4; ++n) acc[n] = (f32x4){0.f, 0.f, 0.f, 0.f};

    const ushort16* xrow = &xs[(wv * 16 + r16) * XPAD + kq * 8];
    #pragma unroll
    for (int kk = 0; kk < 4; ++kk) {
        short8 a = *(const short8*)(xrow + kk * 32);
        #pragma unroll
        for (int n = 0; n < 4; ++n) {
            short8 b = *(const short8*)&wt[(n * 16 + r16) * XPAD + kk * 32 + kq * 8];
            acc[n] = __builtin_amdgcn_mfma_f32_16x16x32_bf16(a, b, acc[n], 0, 0, 0);
        }
    }

    #pragma unroll
    for (int n = 0; n < 4; ++n) {
        #pragma unroll
        for (int j = 0; j < 4; ++j) {
            int gr = block_row + wv * 16 + kq * 4 + j;
            if (gr < N_NODES)
                h2b[(size_t)gr * OUT_CH + n * 16 + r16] = f32_to_bf16(acc[n][j]);
        }
    }
}

// ---------------- gather2: out = b2 + Ahat*h2 ----------------
__global__ __launch_bounds__(256) void gather2_kernel(
    const int* __restrict__ offs, const int* __restrict__ degi,
    const ushort16* __restrict__ ebuf16, const float* __restrict__ dinv,
    const ushort16* __restrict__ h2b, const float* __restrict__ b2,
    float* __restrict__ out) {
    int node = blockIdx.x * 4 + (threadIdx.x >> 6);
    int lane = threadIdx.x & 63;
    if (node >= N_NODES) return;
    float di = dinv[node];
    int beg = offs[node];
    int cnt = degi[node];

    float self = __uint_as_float(((uint32)h2b[(size_t)node * OUT_CH + lane]) << 16);
    float acc = b2[lane] + self * di * di;

    for (int base = 0; base < cnt; base += 64) {
        int m = min(cnt - base, 64);
        int e_l = 0; float w_l = 0.f;
        if (lane < m) {
            e_l = (int)ebuf16[beg + base + lane];
            e_l = min(e_l, N_NODES - 1);          // harden vs poison under replay
            w_l = dinv[e_l] * di;
        }
        int i = 0;
        for (; i + 8 <= m; i += 8) {
            int s0 = RLI(e_l, i),     s1 = RLI(e_l, i + 1);
            int s2 = RLI(e_l, i + 2), s3 = RLI(e_l, i + 3);
            int s4 = RLI(e_l, i + 4), s5 = RLI(e_l, i + 5);
            int s6 = RLI(e_l, i + 6), s7 = RLI(e_l, i + 7);
            float w0 = RLF(w_l, i),     w1 = RLF(w_l, i + 1);
            float w2 = RLF(w_l, i + 2), w3 = RLF(w_l, i + 3);
            float w4 = RLF(w_l, i + 4), w5 = RLF(w_l, i + 5);
            float w6 = RLF(w_l, i + 6), w7 = RLF(w_l, i + 7);
            float v0 = __uint_as_float(((uint32)h2b[(size_t)s0 * OUT_CH + lane]) << 16);
            float v1 = __uint_as_float(((uint32)h2b[(size_t)s1 * OUT_CH + lane]) << 16);
            float v2 = __uint_as_float(((uint32)h2b[(size_t)s2 * OUT_CH + lane]) << 16);
            float v3 = __uint_as_float(((uint32)h2b[(size_t)s3 * OUT_CH + lane]) << 16);
            float v4 = __uint_as_float(((uint32)h2b[(size_t)s4 * OUT_CH + lane]) << 16);
            float v5 = __uint_as_float(((uint32)h2b[(size_t)s5 * OUT_CH + lane]) << 16);
            float v6 = __uint_as_float(((uint32)h2b[(size_t)s6 * OUT_CH + lane]) << 16);
            float v7 = __uint_as_float(((uint32)h2b[(size_t)s7 * OUT_CH + lane]) << 16);
            acc += v0 * w0 + v1 * w1 + v2 * w2 + v3 * w3
                 + v4 * w4 + v5 * w5 + v6 * w6 + v7 * w7;
        }
        for (; i < m; ++i) {
            int s0 = RLI(e_l, i);
            float w0 = RLF(w_l, i);
            float v0 = __uint_as_float(((uint32)h2b[(size_t)s0 * OUT_CH + lane]) << 16);
            acc += v0 * w0;
        }
    }
    out[(size_t)node * OUT_CH + lane] = acc;
}

extern "C" void kernel_launch(void* const* d_in, const int* in_sizes, int n_in,
                              void* d_out, int out_size, void* d_ws, size_t ws_size,
                              hipStream_t stream) {
    const float* x  = (const float*)d_in[0];
    const int*   ei = (const int*)d_in[1];
    const float* W1 = (const float*)d_in[2];
    const float* b1 = (const float*)d_in[3];
    const float* W2 = (const float*)d_in[4];
    const float* b2 = (const float*)d_in[5];
    float* out = (float*)d_out;

    const int E = in_sizes[1] / 2;   // edge_index is [2, E]
    const int* src = ei;
    const int* dst = ei + E;
    const int nA = (E + APB - 1) / APB;

    // workspace layout
    float* dinv   = (float*)d_ws;                 // N
    int* degi     = (int*)(dinv + N_NODES);       // N
    int* offs     = degi + N_NODES;               // N
    int* gcur     = offs + N_NODES;               // NCB
    ushort16* w1t = (ushort16*)(gcur + NCB);      // 128*128
    ushort16* w2t = w1t + 128 * 128;              // 64*128
    ushort16* ebuf16 = w2t + 64 * 128;            // NCB*CAP (u16) — worst-case sized
    uintptr_t p   = (uintptr_t)(ebuf16 + (size_t)NCB * CAP);
    p = (p + 15) & ~(uintptr_t)15;
    ushort16* a1b = (ushort16*)p;                     // N*128 bf16
    uint32* ebuf2 = (uint32*)a1b;                     // NCB*CAP u32, aliases a1b (used before it)
    ushort16* h1b = a1b + (size_t)N_NODES * HID;      // N*128 bf16
    ushort16* h2b = h1b + (size_t)N_NODES * HID;      // N*64 bf16

    hipMemsetAsync(gcur, 0, NCB * sizeof(int), stream);
    build1_kernel<<<nA + 64, 256, 0, stream>>>(src, dst, gcur, ebuf2, E, nA,
                                               W1, W2, w1t, w2t);
    build2_kernel<<<NCB + G1BLK, 256, 0, stream>>>(ebuf2, gcur, ebuf16, offs, degi, dinv,
                                                   x, w1t, h1b);
    gather1_kernel<<<(N_NODES + 3) / 4, 256, 0, stream>>>(offs, degi, ebuf16, dinv, h1b, b1, a1b);
    gemm2_mfma_kernel<<<G1BLK, 256, 0, stream>>>(a1b, w2t, h2b);
    gather2_kernel<<<(N_NODES + 3) / 4, 256, 0, stream>>>(offs, degi, ebuf16, dinv, h2b, b2, out);
}